// Round 10
// baseline (549.555 us; speedup 1.0000x reference)
//
#include <hip/hip_runtime.h>

static constexpr int NBRS = 21;
static constexpr int Nv   = 12288;
static constexpr int BV   = 4 * Nv;            // 49152 rows
static constexpr float BN_EPS = 1e-5f;

typedef __bf16 bf16x4 __attribute__((ext_vector_type(4)));
typedef __bf16 bf16x8 __attribute__((ext_vector_type(8)));
typedef float  f32x4  __attribute__((ext_vector_type(4)));

// ---------------- SPMM (C=8, scalar). MODE: 0: y=acc; 1: y=2acc-x0;
// 2: y=2acc+x0; 3: y=acc+x0-x1
template<int MODE>
__global__ void spmm8_kernel(float* __restrict__ y, const float* __restrict__ x,
                             const float* __restrict__ x0, const float* __restrict__ x1,
                             const float* __restrict__ val, const int* __restrict__ col)
{
    int idx = blockIdx.x * 256 + threadIdx.x;
    int c = idx % 8;
    int v = (idx / 8) % Nv;
    int b = idx / (8 * Nv);
    int e0 = v * NBRS;
    float acc = 0.f;
    #pragma unroll
    for (int j = 0; j < NBRS; ++j) {
        int u = col[e0 + j];
        acc = fmaf(val[e0 + j], x[((size_t)b * Nv + u) * 8 + c], acc);
    }
    if (MODE == 0)      y[idx] = acc;
    else if (MODE == 1) y[idx] = 2.f * acc - x0[idx];
    else if (MODE == 2) y[idx] = fmaf(2.f, acc, x0[idx]);
    else                y[idx] = acc + x0[idx] - x1[idx];
}

// ---------------- SPMM C=64: thread owns (v,q), loops 4 batches.
// Optional fused BN+relu on gathered x and/or on x0 (cheb2 variant).
template<bool CHEB2, bool BNG, bool BNX0>
__global__ __launch_bounds__(256)
void spmm64_kernel(float* __restrict__ y, const float* __restrict__ x,
                   const float* __restrict__ x0,
                   const float* __restrict__ val, const int* __restrict__ col,
                   const float* __restrict__ bn_a, const float* __restrict__ bn_b)
{
    int idx = blockIdx.x * 256 + threadIdx.x;   // over Nv*16
    int q = idx & 15;
    int v = idx >> 4;
    int e0 = v * NBRS;
    const float4* x4 = (const float4*)x;
    float4 a4, b4;
    if (BNG || (CHEB2 && BNX0)) {
        a4 = ((const float4*)bn_a)[q];
        b4 = ((const float4*)bn_b)[q];
    }
    float4 acc[4];
    #pragma unroll
    for (int b = 0; b < 4; ++b) acc[b] = make_float4(0.f, 0.f, 0.f, 0.f);

    #pragma unroll 3
    for (int j = 0; j < NBRS; ++j) {
        const int u = col[e0 + j];
        const float a = val[e0 + j];
        #pragma unroll
        for (int b = 0; b < 4; ++b) {
            float4 xv = x4[(size_t)(b * Nv + u) * 16 + q];
            if (BNG) {
                xv.x = fmaxf(fmaf(xv.x, a4.x, b4.x), 0.f);
                xv.y = fmaxf(fmaf(xv.y, a4.y, b4.y), 0.f);
                xv.z = fmaxf(fmaf(xv.z, a4.z, b4.z), 0.f);
                xv.w = fmaxf(fmaf(xv.w, a4.w, b4.w), 0.f);
            }
            acc[b].x = fmaf(a, xv.x, acc[b].x);
            acc[b].y = fmaf(a, xv.y, acc[b].y);
            acc[b].z = fmaf(a, xv.z, acc[b].z);
            acc[b].w = fmaf(a, xv.w, acc[b].w);
        }
    }
    #pragma unroll
    for (int b = 0; b < 4; ++b) {
        float4 r = acc[b];
        const size_t oi = (size_t)(b * Nv + v) * 16 + q;
        if (CHEB2) {
            float4 pv = ((const float4*)x0)[oi];
            if (BNX0) {
                pv.x = fmaxf(fmaf(pv.x, a4.x, b4.x), 0.f);
                pv.y = fmaxf(fmaf(pv.y, a4.y, b4.y), 0.f);
                pv.z = fmaxf(fmaf(pv.z, a4.z, b4.z), 0.f);
                pv.w = fmaxf(fmaf(pv.w, a4.w, b4.w), 0.f);
            }
            r.x = 2.f * r.x - pv.x;
            r.y = 2.f * r.y - pv.y;
            r.z = 2.f * r.z - pv.z;
            r.w = 2.f * r.w - pv.w;
        }
        ((float4*)y)[oi] = r;
    }
}

// ---------------- conv3 fp32 pre-pack: [3][256][8] -> [256][32] (+ padded bias)
__global__ void pack_conv3_kernel(const float* __restrict__ w, const float* __restrict__ bias,
                                  float* __restrict__ wpack, float* __restrict__ bpack)
{
    int t = blockIdx.x * 256 + threadIdx.x;
    if (t < 256 * 32) {
        int ki = t / 32, c = t % 32;
        int j = c / 8, o = c % 8;
        wpack[t] = (j < 3) ? w[(size_t)j * 2048 + ki * 8 + o] : 0.f;
    }
    if (t < 32) bpack[t] = (t < 8) ? bias[t] : 0.f;
}

// ---------------- mega-pack: all fp32 weights -> fragment-ordered bf16 arena
// arena regions (contiguous): wp1[2048] wp2[49152] wpc1[49152] wpc2[36864]
// wpc3[49152] wp3[8192]; dst = wb + t.
__global__ __launch_bounds__(256)
void pack_all_kernel(const float* __restrict__ w1, const float* __restrict__ w2,
                     const float* __restrict__ c1, const float* __restrict__ c2,
                     const float* __restrict__ c3, const float* __restrict__ wpk,
                     __bf16* __restrict__ wb)
{
    int t = blockIdx.x * 256 + threadIdx.x;
    if (t >= 194560) return;
    const float* src; int KSRC, FOUT, local;
    if (t < 2048)        { src = w1;  KSRC = 24;  FOUT = 64;  local = t; }
    else if (t < 51200)  { src = w2;  KSRC = 192; FOUT = 256; local = t - 2048; }
    else if (t < 100352) { int i = (t - 51200) / 16384;  src = c1 + (size_t)i * 16384;
                           KSRC = 256; FOUT = 64;  local = (t - 51200) % 16384; }
    else if (t < 137216) { int i = (t - 100352) / 12288; src = c2 + (size_t)i * 12288;
                           KSRC = 192; FOUT = 64;  local = (t - 100352) % 12288; }
    else if (t < 186368) { int i = (t - 137216) / 16384; src = c3 + (size_t)i * 16384;
                           KSRC = 64;  FOUT = 256; local = (t - 137216) % 16384; }
    else                 { src = wpk; KSRC = 256; FOUT = 32;  local = t - 186368; }
    const int j    = local & 7;
    const int lane = (local >> 3) & 63;
    const int rest = local >> 9;
    const int NT = FOUT >> 4;
    const int nt = rest % NT;
    const int ks = rest / NT;
    const int k = ks * 32 + (lane >> 4) * 8 + j;
    const int o = nt * 16 + (lane & 15);
    wb[t] = (k < KSRC) ? (__bf16)src[(size_t)k * FOUT + o] : (__bf16)0.f;
}

// ---------------- MFMA GEMM (unchanged from round 9)
template<int FOUT, int KFIN, int KPAD, int FIN, int NSRC,
         bool STATS, bool BN0, bool HAS_BIAS, bool PACKOUT>
__global__ __launch_bounds__(256)
void gemm_mfma_kernel(const float* __restrict__ x0, const float* __restrict__ x1,
                      const float* __restrict__ x2,
                      const __bf16* __restrict__ wp, const float* __restrict__ bias,
                      const float* __restrict__ bn_a, const float* __restrict__ bn_b,
                      float* __restrict__ out, float2* __restrict__ partial)
{
    constexpr int NT    = FOUT / 16;
    constexpr int NSTEP = KPAD / 32;
    constexpr bool COLS = (NT % 4 == 0);
    constexpr int NT2   = COLS ? NT / 4 : NT;
    constexpr int LDKB  = KPAD + 8;
    constexpr int LDC   = FOUT + 4;
    constexpr size_t XS_B  = (size_t)64 * LDKB * 2;
    constexpr size_t RPK_B = COLS ? (size_t)16 * LDC * 4 : 0;
    constexpr size_t SMEM  = XS_B > RPK_B ? XS_B : RPK_B;
    __shared__ __align__(16) char smem[SMEM];
    __bf16* xs = (__bf16*)smem;

    const int tid = threadIdx.x;
    const int m0 = blockIdx.x * 64;

    constexpr int NF4 = 64 * (KPAD / 4);
    for (int f = tid; f < NF4; f += 256) {
        const int r  = f / (KPAD / 4);
        const int ki = (f % (KPAD / 4)) * 4;
        bf16x4 h;
        if (KFIN == KPAD || ki < KFIN) {
            const float* src; int i; int kk;
            if constexpr (NSRC == 1) { src = x0; i = ki; kk = 0; }
            else { kk = ki / FIN; i = ki % FIN; src = (kk == 0) ? x0 : (kk == 1 ? x1 : x2); }
            float4 v = *(const float4*)(src + (size_t)(m0 + r) * FIN + i);
            if constexpr (BN0) {
                if (NSRC == 1 || kk == 0) {
                    const float4 a4 = *(const float4*)(bn_a + i);
                    const float4 b4 = *(const float4*)(bn_b + i);
                    v.x = fmaxf(fmaf(v.x, a4.x, b4.x), 0.f);
                    v.y = fmaxf(fmaf(v.y, a4.y, b4.y), 0.f);
                    v.z = fmaxf(fmaf(v.z, a4.z, b4.z), 0.f);
                    v.w = fmaxf(fmaf(v.w, a4.w, b4.w), 0.f);
                }
            }
            h[0] = (__bf16)v.x; h[1] = (__bf16)v.y; h[2] = (__bf16)v.z; h[3] = (__bf16)v.w;
        } else {
            h[0] = (__bf16)0.f; h[1] = (__bf16)0.f; h[2] = (__bf16)0.f; h[3] = (__bf16)0.f;
        }
        *(bf16x4*)(xs + (size_t)r * LDKB + ki) = h;
    }
    __syncthreads();

    const int lane = tid & 63;
    const int wv   = tid >> 6;
    const int lo   = lane & 15;
    const int hi   = lane >> 4;

    if constexpr (COLS) {
        f32x4 acc[4][NT2];
        #pragma unroll
        for (int mr = 0; mr < 4; ++mr)
            #pragma unroll
            for (int n = 0; n < NT2; ++n) acc[mr][n] = (f32x4){0.f, 0.f, 0.f, 0.f};

        #pragma unroll
        for (int ks = 0; ks < NSTEP; ++ks) {
            bf16x8 bfr[NT2];
            #pragma unroll
            for (int n = 0; n < NT2; ++n)
                bfr[n] = *(const bf16x8*)(wp + ((size_t)(ks * NT + wv * NT2 + n) * 64 + lane) * 8);
            bf16x8 afr[4];
            #pragma unroll
            for (int mr = 0; mr < 4; ++mr)
                afr[mr] = *(const bf16x8*)(xs + (size_t)(mr * 16 + lo) * LDKB + ks * 32 + hi * 8);
            #pragma unroll
            for (int n = 0; n < NT2; ++n)
                #pragma unroll
                for (int mr = 0; mr < 4; ++mr)
                    acc[mr][n] = __builtin_amdgcn_mfma_f32_16x16x32_bf16(afr[mr], bfr[n], acc[mr][n], 0, 0, 0);
        }

        #pragma unroll
        for (int n = 0; n < NT2; ++n) {
            const int o = wv * (FOUT / 4) + n * 16 + lo;
            const float bo = HAS_BIAS ? bias[o] : 0.f;
            #pragma unroll
            for (int mr = 0; mr < 4; ++mr)
                #pragma unroll
                for (int j = 0; j < 4; ++j) acc[mr][n][j] += bo;
        }

        if constexpr (STATS) {
            #pragma unroll
            for (int n = 0; n < NT2; ++n) {
                float s = 0.f, q = 0.f;
                #pragma unroll
                for (int mr = 0; mr < 4; ++mr)
                    #pragma unroll
                    for (int j = 0; j < 4; ++j) {
                        const float v = acc[mr][n][j];
                        s += v; q = fmaf(v, v, q);
                    }
                s += __shfl_xor(s, 16); q += __shfl_xor(q, 16);
                s += __shfl_xor(s, 32); q += __shfl_xor(q, 32);
                if (lane < 16) {
                    const int o = wv * (FOUT / 4) + n * 16 + lo;
                    partial[(size_t)o * gridDim.x + blockIdx.x] = make_float2(s, q);
                }
            }
        }

        float* cs = (float*)smem;
        #pragma unroll
        for (int mr = 0; mr < 4; ++mr) {
            __syncthreads();
            #pragma unroll
            for (int n = 0; n < NT2; ++n) {
                const int o = wv * (FOUT / 4) + n * 16 + lo;
                #pragma unroll
                for (int j = 0; j < 4; ++j)
                    cs[(size_t)(hi * 4 + j) * LDC + o] = acc[mr][n][j];
            }
            __syncthreads();
            for (int t = tid; t < 16 * (FOUT / 4); t += 256) {
                const int rr = t / (FOUT / 4);
                const int c4 = (t % (FOUT / 4)) * 4;
                const float4 v = *(const float4*)(cs + (size_t)rr * LDC + c4);
                *(float4*)(out + (size_t)(m0 + mr * 16 + rr) * FOUT + c4) = v;
            }
        }
    } else {
        f32x4 acc[NT];
        #pragma unroll
        for (int nt = 0; nt < NT; ++nt) acc[nt] = (f32x4){0.f, 0.f, 0.f, 0.f};
        const int arow = wv * 16 + lo;
        #pragma unroll
        for (int ks = 0; ks < NSTEP; ++ks) {
            const bf16x8 a = *(const bf16x8*)(xs + (size_t)arow * LDKB + ks * 32 + hi * 8);
            #pragma unroll
            for (int nt = 0; nt < NT; ++nt) {
                const bf16x8 b = *(const bf16x8*)(wp + ((size_t)(ks * NT + nt) * 64 + lane) * 8);
                acc[nt] = __builtin_amdgcn_mfma_f32_16x16x32_bf16(a, b, acc[nt], 0, 0, 0);
            }
        }
        #pragma unroll
        for (int nt = 0; nt < NT; ++nt) {
            const int o = nt * 16 + lo;
            const float bo = HAS_BIAS ? bias[o] : 0.f;
            #pragma unroll
            for (int j = 0; j < 4; ++j) {
                const float v = acc[nt][j] + bo;
                const int m = m0 + wv * 16 + hi * 4 + j;
                if constexpr (PACKOUT) {
                    const int zj = o >> 3;
                    if (zj < 3) out[((size_t)zj * BV + m) * 8 + (o & 7)] = v;
                } else {
                    out[(size_t)m * FOUT + o] = v;
                }
            }
        }
    }
}

// ---------------- BN finalize: one block per channel, coalesced over [C][nblk]
__global__ __launch_bounds__(256)
void bn_finalize_kernel(const float2* __restrict__ partial,
                        const float* __restrict__ g, const float* __restrict__ b,
                        float* __restrict__ a_out, float* __restrict__ b_out,
                        float invN, int nblk)
{
    __shared__ float2 red[4];
    const int c = blockIdx.x;
    const float2* p = partial + (size_t)c * nblk;
    float s = 0.f, ss = 0.f;
    for (int k = threadIdx.x; k < nblk; k += 256) {
        const float2 v = p[k];
        s += v.x; ss += v.y;
    }
    #pragma unroll
    for (int off = 32; off > 0; off >>= 1) {
        s  += __shfl_down(s, off);
        ss += __shfl_down(ss, off);
    }
    if ((threadIdx.x & 63) == 0) red[threadIdx.x >> 6] = make_float2(s, ss);
    __syncthreads();
    if (threadIdx.x == 0) {
        float ts = 0.f, tq = 0.f;
        #pragma unroll
        for (int i = 0; i < 4; ++i) { ts += red[i].x; tq += red[i].y; }
        const float m = ts * invN;
        const float var = tq * invN - m * m;
        const float a = g[c] * rsqrtf(var + BN_EPS);
        a_out[c] = a;
        b_out[c] = b[c] - m * a;
    }
}

// ---------------- BN apply (float4). BASEBN: base gets relu(BN2(base)) first.
template<int C, bool RELU, bool ADD, bool BASEBN>
__global__ __launch_bounds__(256)
void bn_apply_kernel(float* __restrict__ out, const float* __restrict__ x,
                     const float* __restrict__ base,
                     const float* __restrict__ bn_a, const float* __restrict__ bn_b,
                     const float* __restrict__ bn_a2, const float* __restrict__ bn_b2)
{
    int i = blockIdx.x * 256 + threadIdx.x;   // float4 index
    float4 v = ((const float4*)x)[i];
    int c0 = (i * 4) % C;
    float4 a4 = *reinterpret_cast<const float4*>(bn_a + c0);
    float4 b4 = *reinterpret_cast<const float4*>(bn_b + c0);
    float4 r;
    r.x = fmaf(v.x, a4.x, b4.x);
    r.y = fmaf(v.y, a4.y, b4.y);
    r.z = fmaf(v.z, a4.z, b4.z);
    r.w = fmaf(v.w, a4.w, b4.w);
    if (ADD) {
        float4 bvv = ((const float4*)base)[i];
        if (BASEBN) {
            float4 p4 = *reinterpret_cast<const float4*>(bn_a2 + c0);
            float4 q4 = *reinterpret_cast<const float4*>(bn_b2 + c0);
            bvv.x = fmaxf(fmaf(bvv.x, p4.x, q4.x), 0.f);
            bvv.y = fmaxf(fmaf(bvv.y, p4.y, q4.y), 0.f);
            bvv.z = fmaxf(fmaf(bvv.z, p4.z, q4.z), 0.f);
            bvv.w = fmaxf(fmaf(bvv.w, p4.w, q4.w), 0.f);
        }
        r.x += bvv.x; r.y += bvv.y; r.z += bvv.z; r.w += bvv.w;
    }
    if (RELU) {
        r.x = fmaxf(r.x, 0.f); r.y = fmaxf(r.y, 0.f);
        r.z = fmaxf(r.z, 0.f); r.w = fmaxf(r.w, 0.f);
    }
    ((float4*)out)[i] = r;
}

extern "C" void kernel_launch(void* const* d_in, const int* in_sizes, int n_in,
                              void* d_out, int out_size, void* d_ws, size_t ws_size,
                              hipStream_t stream)
{
    const float* x       = (const float*)d_in[0];
    const int*   col     = (const int*)  d_in[2];
    const float* eval_   = (const float*)d_in[3];
    const float* conv1_w = (const float*)d_in[4];
    const float* conv1_b = (const float*)d_in[5];
    const float* bn1_g   = (const float*)d_in[6];
    const float* bn1_b   = (const float*)d_in[7];
    const float* conv2_w = (const float*)d_in[8];
    const float* conv2_b = (const float*)d_in[9];
    const float* bn2_g   = (const float*)d_in[10];
    const float* bn2_b   = (const float*)d_in[11];
    const float* bt_c1w  = (const float*)d_in[12];
    const float* bt_c1b  = (const float*)d_in[13];
    const float* bt_c2w  = (const float*)d_in[14];
    const float* bt_c2b  = (const float*)d_in[15];
    const float* bt_c3w  = (const float*)d_in[16];
    const float* bt_c3b  = (const float*)d_in[17];
    const float* btbn1g  = (const float*)d_in[18];
    const float* btbn1b  = (const float*)d_in[19];
    const float* btbn2g  = (const float*)d_in[20];
    const float* btbn2b  = (const float*)d_in[21];
    const float* btbn3g  = (const float*)d_in[22];
    const float* btbn3b  = (const float*)d_in[23];
    const float* conv3_w = (const float*)d_in[24];
    const float* conv3_b = (const float*)d_in[25];
    float* out = (float*)d_out;

    float* ws = (float*)d_ws;
    float* h2    = ws;                         // BV*256 (raw conv2 out, then residual trunk)
    float* y3    = h2 + (size_t)BV * 256;      // BV*256 (aliased as stats partial)
    float* t64a  = y3 + (size_t)BV * 256;      // BV*64
    float* t64b  = t64a + (size_t)BV * 64;     // BV*64
    float* t64c  = t64b + (size_t)BV * 64;     // BV*64
    float* t64d  = t64c + (size_t)BV * 64;     // BV*64
    float* aarr  = t64d + (size_t)BV * 64;     // 11*256
    float* barr  = aarr + 11 * 256;            // 11*256
    float* wpack = barr + 11 * 256;            // 256*32 fp32 (conv3 packed)
    float* bpack = wpack + 256 * 32;           // 32
    __bf16* wb   = (__bf16*)(bpack + 32);      // bf16 weight arena (contiguous regions)
    __bf16* wp1  = wb;                         // 2048
    __bf16* wp2  = wp1 + 2048;                 // 49152
    __bf16* wpc1 = wp2 + 49152;                // 49152
    __bf16* wpc2 = wpc1 + 49152;               // 36864
    __bf16* wpc3 = wpc2 + 36864;               // 49152
    __bf16* wp3  = wpc3 + 49152;               // 8192
    float2* partY = (float2*)y3;
    float2* partC = (float2*)t64c;

    const float invN = 1.f / (float)BV;
    const int NGB  = BV / 64;                  // 768 MFMA GEMM blocks
    const int NAPP = BV / 4;                   // C=256 bn_apply blocks
    const int NSP64 = Nv * 16 / 256;           // 768 spmm64 blocks

    // ---------- packing: 2 launches ----------
    pack_conv3_kernel<<<32, 256, 0, stream>>>(conv3_w, conv3_b, wpack, bpack);
    pack_all_kernel<<<760, 256, 0, stream>>>(conv1_w, conv2_w, bt_c1w, bt_c2w, bt_c3w, wpack, wb);

    // ---------- Stage A: conv1 (8 -> 64), K=3 ----------
    spmm8_kernel<0><<<BV * 8 / 256, 256, 0, stream>>>(t64a, x, nullptr, nullptr, eval_, col);
    spmm8_kernel<1><<<BV * 8 / 256, 256, 0, stream>>>(t64b, t64a, x, nullptr, eval_, col);
    gemm_mfma_kernel<64, 24, 32, 8, 3, true, false, true, false>
        <<<NGB, 256, 0, stream>>>(x, t64a, t64b, wp1, conv1_b, nullptr, nullptr, t64c, partY);
    bn_finalize_kernel<<<64, 256, 0, stream>>>(partY, bn1_g, bn1_b, aarr, barr, invN, NGB);

    // ---------- Stage B: conv2 (64 -> 256), K=3; h2 stays RAW (BN2 fused at readers)
    spmm64_kernel<false, true, false><<<NSP64, 256, 0, stream>>>(t64a, t64c, nullptr, eval_, col, aarr, barr);
    spmm64_kernel<true, false, true ><<<NSP64, 256, 0, stream>>>(t64b, t64a, t64c, eval_, col, aarr, barr);
    gemm_mfma_kernel<256, 192, 192, 64, 3, true, true, true, false>
        <<<NGB, 256, 0, stream>>>(t64c, t64a, t64b, wp2, conv2_b, aarr, barr, h2, partY);
    bn_finalize_kernel<<<256, 256, 0, stream>>>(partY, bn2_g, bn2_b, aarr + 256, barr + 256, invN, NGB);

    // ---------- Stage C: 3 bottlenecks ----------
    for (int i = 0; i < 3; ++i) {
        float* aA = aarr + (2 + i * 3) * 256; float* bA = barr + (2 + i * 3) * 256;
        float* aB = aarr + (3 + i * 3) * 256; float* bB = barr + (3 + i * 3) * 256;
        float* aC = aarr + (4 + i * 3) * 256; float* bC = barr + (4 + i * 3) * 256;

        // cheb1: K=1, 256->64. For i==0 the input is raw conv2 out -> fuse BN2.
        if (i == 0)
            gemm_mfma_kernel<64, 256, 256, 256, 1, true, true, true, false>
                <<<NGB, 256, 0, stream>>>(h2, nullptr, nullptr, wpc1,
                                          bt_c1b, aarr + 256, barr + 256, t64c, partY);
        else
            gemm_mfma_kernel<64, 256, 256, 256, 1, true, false, true, false>
                <<<NGB, 256, 0, stream>>>(h2, nullptr, nullptr, wpc1 + (size_t)i * 16384,
                                          bt_c1b + i * 64, nullptr, nullptr, t64c, partY);
        bn_finalize_kernel<<<64, 256, 0, stream>>>(partY, btbn1g + i * 64, btbn1b + i * 64, aA, bA, invN, NGB);

        // cheb2: K=3, 64->64; BN1 fused into gathers and x0-staging
        spmm64_kernel<false, true, false><<<NSP64, 256, 0, stream>>>(t64a, t64c, nullptr, eval_, col, aA, bA);
        spmm64_kernel<true, false, true ><<<NSP64, 256, 0, stream>>>(t64b, t64a, t64c, eval_, col, aA, bA);
        gemm_mfma_kernel<64, 192, 192, 64, 3, true, true, true, false>
            <<<NGB, 256, 0, stream>>>(t64c, t64a, t64b, wpc2 + (size_t)i * 12288,
                                      bt_c2b + i * 64, aA, bA, t64d, partY);
        bn_finalize_kernel<<<64, 256, 0, stream>>>(partY, btbn2g + i * 64, btbn2b + i * 64, aB, bB, invN, NGB);

        // cheb3: K=1, 64->256; BN2 fused into x0-staging; stats partial -> t64c
        gemm_mfma_kernel<256, 64, 64, 64, 1, true, true, true, false>
            <<<NGB, 256, 0, stream>>>(t64d, nullptr, nullptr, wpc3 + (size_t)i * 16384,
                                      bt_c3b + i * 256, aB, bB, y3, partC);
        bn_finalize_kernel<<<256, 256, 0, stream>>>(partC, btbn3g + i * 256, btbn3b + i * 256, aC, bC, invN, NGB);

        // residual: h2 = BN3(y3) + base; base is raw conv2 out for i==0 (apply BN2+relu)
        if (i == 0)
            bn_apply_kernel<256, false, true, true><<<NAPP, 256, 0, stream>>>(
                h2, y3, h2, aC, bC, aarr + 256, barr + 256);
        else
            bn_apply_kernel<256, false, true, false><<<NAPP, 256, 0, stream>>>(
                h2, y3, h2, aC, bC, nullptr, nullptr);
    }

    // ---------- Stage D: conv3 (256 -> 8), commuted: out = z0 - z2 + L(z1 + 2*L*z2) ----------
    float* z0 = t64a;
    float* z1 = z0 + (size_t)BV * 8;
    float* z2 = z1 + (size_t)BV * 8;
    float* ee = z2 + (size_t)BV * 8;

    gemm_mfma_kernel<32, 256, 256, 256, 1, false, false, true, true>
        <<<NGB, 256, 0, stream>>>(h2, nullptr, nullptr, wp3, bpack, nullptr, nullptr, z0, nullptr);

    spmm8_kernel<2><<<BV * 8 / 256, 256, 0, stream>>>(ee, z2, z1, nullptr, eval_, col);
    spmm8_kernel<3><<<BV * 8 / 256, 256, 0, stream>>>(out, ee, z0, z2, eval_, col);

    (void)in_sizes; (void)n_in; (void)out_size; (void)ws_size;
}

// Round 11
// 548.480 us; speedup vs baseline: 1.0020x; 1.0020x over previous
//
#include <hip/hip_runtime.h>

static constexpr int NBRS = 21;
static constexpr int Nv   = 12288;
static constexpr int BV   = 4 * Nv;            // 49152 rows
static constexpr float BN_EPS = 1e-5f;

typedef __bf16 bf16x4 __attribute__((ext_vector_type(4)));
typedef __bf16 bf16x8 __attribute__((ext_vector_type(8)));
typedef float  f32x4  __attribute__((ext_vector_type(4)));

// ---------------- SPMM (C=8, scalar). MODE: 0: y=acc; 1: y=2acc-x0;
// 2: y=2acc+x0; 3: y=acc+x0-x1
template<int MODE>
__global__ void spmm8_kernel(float* __restrict__ y, const float* __restrict__ x,
                             const float* __restrict__ x0, const float* __restrict__ x1,
                             const float* __restrict__ val, const int* __restrict__ col)
{
    int idx = blockIdx.x * 256 + threadIdx.x;
    int c = idx % 8;
    int v = (idx / 8) % Nv;
    int b = idx / (8 * Nv);
    int e0 = v * NBRS;
    float acc = 0.f;
    #pragma unroll
    for (int j = 0; j < NBRS; ++j) {
        int u = col[e0 + j];
        acc = fmaf(val[e0 + j], x[((size_t)b * Nv + u) * 8 + c], acc);
    }
    if (MODE == 0)      y[idx] = acc;
    else if (MODE == 1) y[idx] = 2.f * acc - x0[idx];
    else if (MODE == 2) y[idx] = fmaf(2.f, acc, x0[idx]);
    else                y[idx] = acc + x0[idx] - x1[idx];
}

// ---------------- SPMM C=64: thread owns (v,q), loops 4 batches.
// Optional fused BN+relu on gathered x and/or on x0 (cheb2 variant).
template<bool CHEB2, bool BNG, bool BNX0>
__global__ __launch_bounds__(256)
void spmm64_kernel(float* __restrict__ y, const float* __restrict__ x,
                   const float* __restrict__ x0,
                   const float* __restrict__ val, const int* __restrict__ col,
                   const float* __restrict__ bn_a, const float* __restrict__ bn_b)
{
    int idx = blockIdx.x * 256 + threadIdx.x;   // over Nv*16
    int q = idx & 15;
    int v = idx >> 4;
    int e0 = v * NBRS;
    const float4* x4 = (const float4*)x;
    float4 a4, b4;
    if (BNG || (CHEB2 && BNX0)) {
        a4 = ((const float4*)bn_a)[q];
        b4 = ((const float4*)bn_b)[q];
    }
    float4 acc[4];
    #pragma unroll
    for (int b = 0; b < 4; ++b) acc[b] = make_float4(0.f, 0.f, 0.f, 0.f);

    #pragma unroll 3
    for (int j = 0; j < NBRS; ++j) {
        const int u = col[e0 + j];
        const float a = val[e0 + j];
        #pragma unroll
        for (int b = 0; b < 4; ++b) {
            float4 xv = x4[(size_t)(b * Nv + u) * 16 + q];
            if (BNG) {
                xv.x = fmaxf(fmaf(xv.x, a4.x, b4.x), 0.f);
                xv.y = fmaxf(fmaf(xv.y, a4.y, b4.y), 0.f);
                xv.z = fmaxf(fmaf(xv.z, a4.z, b4.z), 0.f);
                xv.w = fmaxf(fmaf(xv.w, a4.w, b4.w), 0.f);
            }
            acc[b].x = fmaf(a, xv.x, acc[b].x);
            acc[b].y = fmaf(a, xv.y, acc[b].y);
            acc[b].z = fmaf(a, xv.z, acc[b].z);
            acc[b].w = fmaf(a, xv.w, acc[b].w);
        }
    }
    #pragma unroll
    for (int b = 0; b < 4; ++b) {
        float4 r = acc[b];
        const size_t oi = (size_t)(b * Nv + v) * 16 + q;
        if (CHEB2) {
            float4 pv = ((const float4*)x0)[oi];
            if (BNX0) {
                pv.x = fmaxf(fmaf(pv.x, a4.x, b4.x), 0.f);
                pv.y = fmaxf(fmaf(pv.y, a4.y, b4.y), 0.f);
                pv.z = fmaxf(fmaf(pv.z, a4.z, b4.z), 0.f);
                pv.w = fmaxf(fmaf(pv.w, a4.w, b4.w), 0.f);
            }
            r.x = 2.f * r.x - pv.x;
            r.y = 2.f * r.y - pv.y;
            r.z = 2.f * r.z - pv.z;
            r.w = 2.f * r.w - pv.w;
        }
        ((float4*)y)[oi] = r;
    }
}

// ---------------- conv3 fp32 pre-pack: [3][256][8] -> [256][32] (+ padded bias)
__global__ void pack_conv3_kernel(const float* __restrict__ w, const float* __restrict__ bias,
                                  float* __restrict__ wpack, float* __restrict__ bpack)
{
    int t = blockIdx.x * 256 + threadIdx.x;
    if (t < 256 * 32) {
        int ki = t / 32, c = t % 32;
        int j = c / 8, o = c % 8;
        wpack[t] = (j < 3) ? w[(size_t)j * 2048 + ki * 8 + o] : 0.f;
    }
    if (t < 32) bpack[t] = (t < 8) ? bias[t] : 0.f;
}

// ---------------- mega-pack: all fp32 weights -> fragment-ordered bf16 arena
// arena regions (contiguous): wp1[2048] wp2[49152] wpc1[49152] wpc2[36864]
// wpc3[49152] wp3[8192]; dst = wb + t.
__global__ __launch_bounds__(256)
void pack_all_kernel(const float* __restrict__ w1, const float* __restrict__ w2,
                     const float* __restrict__ c1, const float* __restrict__ c2,
                     const float* __restrict__ c3, const float* __restrict__ wpk,
                     __bf16* __restrict__ wb)
{
    int t = blockIdx.x * 256 + threadIdx.x;
    if (t >= 194560) return;
    const float* src; int KSRC, FOUT, local;
    if (t < 2048)        { src = w1;  KSRC = 24;  FOUT = 64;  local = t; }
    else if (t < 51200)  { src = w2;  KSRC = 192; FOUT = 256; local = t - 2048; }
    else if (t < 100352) { int i = (t - 51200) / 16384;  src = c1 + (size_t)i * 16384;
                           KSRC = 256; FOUT = 64;  local = (t - 51200) % 16384; }
    else if (t < 137216) { int i = (t - 100352) / 12288; src = c2 + (size_t)i * 12288;
                           KSRC = 192; FOUT = 64;  local = (t - 100352) % 12288; }
    else if (t < 186368) { int i = (t - 137216) / 16384; src = c3 + (size_t)i * 16384;
                           KSRC = 64;  FOUT = 256; local = (t - 137216) % 16384; }
    else                 { src = wpk; KSRC = 256; FOUT = 32;  local = t - 186368; }
    const int j    = local & 7;
    const int lane = (local >> 3) & 63;
    const int rest = local >> 9;
    const int NT = FOUT >> 4;
    const int nt = rest % NT;
    const int ks = rest / NT;
    const int k = ks * 32 + (lane >> 4) * 8 + j;
    const int o = nt * 16 + (lane & 15);
    wb[t] = (k < KSRC) ? (__bf16)src[(size_t)k * FOUT + o] : (__bf16)0.f;
}

// ---------------- MFMA GEMM (unchanged from round 9)
template<int FOUT, int KFIN, int KPAD, int FIN, int NSRC,
         bool STATS, bool BN0, bool HAS_BIAS, bool PACKOUT>
__global__ __launch_bounds__(256)
void gemm_mfma_kernel(const float* __restrict__ x0, const float* __restrict__ x1,
                      const float* __restrict__ x2,
                      const __bf16* __restrict__ wp, const float* __restrict__ bias,
                      const float* __restrict__ bn_a, const float* __restrict__ bn_b,
                      float* __restrict__ out, float2* __restrict__ partial)
{
    constexpr int NT    = FOUT / 16;
    constexpr int NSTEP = KPAD / 32;
    constexpr bool COLS = (NT % 4 == 0);
    constexpr int NT2   = COLS ? NT / 4 : NT;
    constexpr int LDKB  = KPAD + 8;
    constexpr int LDC   = FOUT + 4;
    constexpr size_t XS_B  = (size_t)64 * LDKB * 2;
    constexpr size_t RPK_B = COLS ? (size_t)16 * LDC * 4 : 0;
    constexpr size_t SMEM  = XS_B > RPK_B ? XS_B : RPK_B;
    __shared__ __align__(16) char smem[SMEM];
    __bf16* xs = (__bf16*)smem;

    const int tid = threadIdx.x;
    const int m0 = blockIdx.x * 64;

    constexpr int NF4 = 64 * (KPAD / 4);
    for (int f = tid; f < NF4; f += 256) {
        const int r  = f / (KPAD / 4);
        const int ki = (f % (KPAD / 4)) * 4;
        bf16x4 h;
        if (KFIN == KPAD || ki < KFIN) {
            const float* src; int i; int kk;
            if constexpr (NSRC == 1) { src = x0; i = ki; kk = 0; }
            else { kk = ki / FIN; i = ki % FIN; src = (kk == 0) ? x0 : (kk == 1 ? x1 : x2); }
            float4 v = *(const float4*)(src + (size_t)(m0 + r) * FIN + i);
            if constexpr (BN0) {
                if (NSRC == 1 || kk == 0) {
                    const float4 a4 = *(const float4*)(bn_a + i);
                    const float4 b4 = *(const float4*)(bn_b + i);
                    v.x = fmaxf(fmaf(v.x, a4.x, b4.x), 0.f);
                    v.y = fmaxf(fmaf(v.y, a4.y, b4.y), 0.f);
                    v.z = fmaxf(fmaf(v.z, a4.z, b4.z), 0.f);
                    v.w = fmaxf(fmaf(v.w, a4.w, b4.w), 0.f);
                }
            }
            h[0] = (__bf16)v.x; h[1] = (__bf16)v.y; h[2] = (__bf16)v.z; h[3] = (__bf16)v.w;
        } else {
            h[0] = (__bf16)0.f; h[1] = (__bf16)0.f; h[2] = (__bf16)0.f; h[3] = (__bf16)0.f;
        }
        *(bf16x4*)(xs + (size_t)r * LDKB + ki) = h;
    }
    __syncthreads();

    const int lane = tid & 63;
    const int wv   = tid >> 6;
    const int lo   = lane & 15;
    const int hi   = lane >> 4;

    if constexpr (COLS) {
        f32x4 acc[4][NT2];
        #pragma unroll
        for (int mr = 0; mr < 4; ++mr)
            #pragma unroll
            for (int n = 0; n < NT2; ++n) acc[mr][n] = (f32x4){0.f, 0.f, 0.f, 0.f};

        #pragma unroll
        for (int ks = 0; ks < NSTEP; ++ks) {
            bf16x8 bfr[NT2];
            #pragma unroll
            for (int n = 0; n < NT2; ++n)
                bfr[n] = *(const bf16x8*)(wp + ((size_t)(ks * NT + wv * NT2 + n) * 64 + lane) * 8);
            bf16x8 afr[4];
            #pragma unroll
            for (int mr = 0; mr < 4; ++mr)
                afr[mr] = *(const bf16x8*)(xs + (size_t)(mr * 16 + lo) * LDKB + ks * 32 + hi * 8);
            #pragma unroll
            for (int n = 0; n < NT2; ++n)
                #pragma unroll
                for (int mr = 0; mr < 4; ++mr)
                    acc[mr][n] = __builtin_amdgcn_mfma_f32_16x16x32_bf16(afr[mr], bfr[n], acc[mr][n], 0, 0, 0);
        }

        #pragma unroll
        for (int n = 0; n < NT2; ++n) {
            const int o = wv * (FOUT / 4) + n * 16 + lo;
            const float bo = HAS_BIAS ? bias[o] : 0.f;
            #pragma unroll
            for (int mr = 0; mr < 4; ++mr)
                #pragma unroll
                for (int j = 0; j < 4; ++j) acc[mr][n][j] += bo;
        }

        if constexpr (STATS) {
            #pragma unroll
            for (int n = 0; n < NT2; ++n) {
                float s = 0.f, q = 0.f;
                #pragma unroll
                for (int mr = 0; mr < 4; ++mr)
                    #pragma unroll
                    for (int j = 0; j < 4; ++j) {
                        const float v = acc[mr][n][j];
                        s += v; q = fmaf(v, v, q);
                    }
                s += __shfl_xor(s, 16); q += __shfl_xor(q, 16);
                s += __shfl_xor(s, 32); q += __shfl_xor(q, 32);
                if (lane < 16) {
                    const int o = wv * (FOUT / 4) + n * 16 + lo;
                    partial[(size_t)o * gridDim.x + blockIdx.x] = make_float2(s, q);
                }
            }
        }

        float* cs = (float*)smem;
        #pragma unroll
        for (int mr = 0; mr < 4; ++mr) {
            __syncthreads();
            #pragma unroll
            for (int n = 0; n < NT2; ++n) {
                const int o = wv * (FOUT / 4) + n * 16 + lo;
                #pragma unroll
                for (int j = 0; j < 4; ++j)
                    cs[(size_t)(hi * 4 + j) * LDC + o] = acc[mr][n][j];
            }
            __syncthreads();
            for (int t = tid; t < 16 * (FOUT / 4); t += 256) {
                const int rr = t / (FOUT / 4);
                const int c4 = (t % (FOUT / 4)) * 4;
                const float4 v = *(const float4*)(cs + (size_t)rr * LDC + c4);
                *(float4*)(out + (size_t)(m0 + mr * 16 + rr) * FOUT + c4) = v;
            }
        }
    } else {
        f32x4 acc[NT];
        #pragma unroll
        for (int nt = 0; nt < NT; ++nt) acc[nt] = (f32x4){0.f, 0.f, 0.f, 0.f};
        const int arow = wv * 16 + lo;
        #pragma unroll
        for (int ks = 0; ks < NSTEP; ++ks) {
            const bf16x8 a = *(const bf16x8*)(xs + (size_t)arow * LDKB + ks * 32 + hi * 8);
            #pragma unroll
            for (int nt = 0; nt < NT; ++nt) {
                const bf16x8 b = *(const bf16x8*)(wp + ((size_t)(ks * NT + nt) * 64 + lane) * 8);
                acc[nt] = __builtin_amdgcn_mfma_f32_16x16x32_bf16(a, b, acc[nt], 0, 0, 0);
            }
        }
        #pragma unroll
        for (int nt = 0; nt < NT; ++nt) {
            const int o = nt * 16 + lo;
            const float bo = HAS_BIAS ? bias[o] : 0.f;
            #pragma unroll
            for (int j = 0; j < 4; ++j) {
                const float v = acc[nt][j] + bo;
                const int m = m0 + wv * 16 + hi * 4 + j;
                if constexpr (PACKOUT) {
                    const int zj = o >> 3;
                    if (zj < 3) out[((size_t)zj * BV + m) * 8 + (o & 7)] = v;
                } else {
                    out[(size_t)m * FOUT + o] = v;
                }
            }
        }
    }
}

// ---------------- BN finalize: one block per channel, coalesced over [C][nblk]
__global__ __launch_bounds__(256)
void bn_finalize_kernel(const float2* __restrict__ partial,
                        const float* __restrict__ g, const float* __restrict__ b,
                        float* __restrict__ a_out, float* __restrict__ b_out,
                        float invN, int nblk)
{
    __shared__ float2 red[4];
    const int c = blockIdx.x;
    const float2* p = partial + (size_t)c * nblk;
    float s = 0.f, ss = 0.f;
    for (int k = threadIdx.x; k < nblk; k += 256) {
        const float2 v = p[k];
        s += v.x; ss += v.y;
    }
    #pragma unroll
    for (int off = 32; off > 0; off >>= 1) {
        s  += __shfl_down(s, off);
        ss += __shfl_down(ss, off);
    }
    if ((threadIdx.x & 63) == 0) red[threadIdx.x >> 6] = make_float2(s, ss);
    __syncthreads();
    if (threadIdx.x == 0) {
        float ts = 0.f, tq = 0.f;
        #pragma unroll
        for (int i = 0; i < 4; ++i) { ts += red[i].x; tq += red[i].y; }
        const float m = ts * invN;
        const float var = tq * invN - m * m;
        const float a = g[c] * rsqrtf(var + BN_EPS);
        a_out[c] = a;
        b_out[c] = b[c] - m * a;
    }
}

// ---------------- BN apply (float4). BASEBN: base gets relu(BN2(base)) first.
template<int C, bool RELU, bool ADD, bool BASEBN>
__global__ __launch_bounds__(256)
void bn_apply_kernel(float* __restrict__ out, const float* __restrict__ x,
                     const float* __restrict__ base,
                     const float* __restrict__ bn_a, const float* __restrict__ bn_b,
                     const float* __restrict__ bn_a2, const float* __restrict__ bn_b2)
{
    int i = blockIdx.x * 256 + threadIdx.x;   // float4 index
    float4 v = ((const float4*)x)[i];
    int c0 = (i * 4) % C;
    float4 a4 = *reinterpret_cast<const float4*>(bn_a + c0);
    float4 b4 = *reinterpret_cast<const float4*>(bn_b + c0);
    float4 r;
    r.x = fmaf(v.x, a4.x, b4.x);
    r.y = fmaf(v.y, a4.y, b4.y);
    r.z = fmaf(v.z, a4.z, b4.z);
    r.w = fmaf(v.w, a4.w, b4.w);
    if (ADD) {
        float4 bvv = ((const float4*)base)[i];
        if (BASEBN) {
            float4 p4 = *reinterpret_cast<const float4*>(bn_a2 + c0);
            float4 q4 = *reinterpret_cast<const float4*>(bn_b2 + c0);
            bvv.x = fmaxf(fmaf(bvv.x, p4.x, q4.x), 0.f);
            bvv.y = fmaxf(fmaf(bvv.y, p4.y, q4.y), 0.f);
            bvv.z = fmaxf(fmaf(bvv.z, p4.z, q4.z), 0.f);
            bvv.w = fmaxf(fmaf(bvv.w, p4.w, q4.w), 0.f);
        }
        r.x += bvv.x; r.y += bvv.y; r.z += bvv.z; r.w += bvv.w;
    }
    if (RELU) {
        r.x = fmaxf(r.x, 0.f); r.y = fmaxf(r.y, 0.f);
        r.z = fmaxf(r.z, 0.f); r.w = fmaxf(r.w, 0.f);
    }
    ((float4*)out)[i] = r;
}

extern "C" void kernel_launch(void* const* d_in, const int* in_sizes, int n_in,
                              void* d_out, int out_size, void* d_ws, size_t ws_size,
                              hipStream_t stream)
{
    const float* x       = (const float*)d_in[0];
    const int*   col     = (const int*)  d_in[2];
    const float* eval_   = (const float*)d_in[3];
    const float* conv1_w = (const float*)d_in[4];
    const float* conv1_b = (const float*)d_in[5];
    const float* bn1_g   = (const float*)d_in[6];
    const float* bn1_b   = (const float*)d_in[7];
    const float* conv2_w = (const float*)d_in[8];
    const float* conv2_b = (const float*)d_in[9];
    const float* bn2_g   = (const float*)d_in[10];
    const float* bn2_b   = (const float*)d_in[11];
    const float* bt_c1w  = (const float*)d_in[12];
    const float* bt_c1b  = (const float*)d_in[13];
    const float* bt_c2w  = (const float*)d_in[14];
    const float* bt_c2b  = (const float*)d_in[15];
    const float* bt_c3w  = (const float*)d_in[16];
    const float* bt_c3b  = (const float*)d_in[17];
    const float* btbn1g  = (const float*)d_in[18];
    const float* btbn1b  = (const float*)d_in[19];
    const float* btbn2g  = (const float*)d_in[20];
    const float* btbn2b  = (const float*)d_in[21];
    const float* btbn3g  = (const float*)d_in[22];
    const float* btbn3b  = (const float*)d_in[23];
    const float* conv3_w = (const float*)d_in[24];
    const float* conv3_b = (const float*)d_in[25];
    float* out = (float*)d_out;

    float* ws = (float*)d_ws;
    float* h2    = ws;                         // BV*256 (raw conv2 out, then residual trunk)
    float* y3    = h2 + (size_t)BV * 256;      // BV*256 (aliased as stats partial)
    float* t64a  = y3 + (size_t)BV * 256;      // BV*64
    float* t64b  = t64a + (size_t)BV * 64;     // BV*64
    float* t64c  = t64b + (size_t)BV * 64;     // BV*64
    float* t64d  = t64c + (size_t)BV * 64;     // BV*64
    float* aarr  = t64d + (size_t)BV * 64;     // 11*256
    float* barr  = aarr + 11 * 256;            // 11*256
    float* wpack = barr + 11 * 256;            // 256*32 fp32 (conv3 packed)
    float* bpack = wpack + 256 * 32;           // 32
    __bf16* wb   = (__bf16*)(bpack + 32);      // bf16 weight arena (contiguous regions)
    __bf16* wp1  = wb;                         // 2048
    __bf16* wp2  = wp1 + 2048;                 // 49152
    __bf16* wpc1 = wp2 + 49152;                // 49152
    __bf16* wpc2 = wpc1 + 49152;               // 36864
    __bf16* wpc3 = wpc2 + 36864;               // 49152
    __bf16* wp3  = wpc3 + 49152;               // 8192
    float2* partY = (float2*)y3;
    float2* partC = (float2*)t64c;

    const float invN = 1.f / (float)BV;
    const int NGB  = BV / 64;                  // 768 MFMA GEMM blocks
    const int NAPP = BV / 4;                   // C=256 bn_apply blocks
    const int NSP64 = Nv * 16 / 256;           // 768 spmm64 blocks

    // ---------- packing: 2 launches ----------
    pack_conv3_kernel<<<32, 256, 0, stream>>>(conv3_w, conv3_b, wpack, bpack);
    pack_all_kernel<<<760, 256, 0, stream>>>(conv1_w, conv2_w, bt_c1w, bt_c2w, bt_c3w, wpack, wb);

    // ---------- Stage A: conv1 (8 -> 64), K=3 ----------
    spmm8_kernel<0><<<BV * 8 / 256, 256, 0, stream>>>(t64a, x, nullptr, nullptr, eval_, col);
    spmm8_kernel<1><<<BV * 8 / 256, 256, 0, stream>>>(t64b, t64a, x, nullptr, eval_, col);
    gemm_mfma_kernel<64, 24, 32, 8, 3, true, false, true, false>
        <<<NGB, 256, 0, stream>>>(x, t64a, t64b, wp1, conv1_b, nullptr, nullptr, t64c, partY);
    bn_finalize_kernel<<<64, 256, 0, stream>>>(partY, bn1_g, bn1_b, aarr, barr, invN, NGB);

    // ---------- Stage B: conv2 (64 -> 256), K=3; h2 stays RAW (BN2 fused at readers)
    spmm64_kernel<false, true, false><<<NSP64, 256, 0, stream>>>(t64a, t64c, nullptr, eval_, col, aarr, barr);
    spmm64_kernel<true, false, true ><<<NSP64, 256, 0, stream>>>(t64b, t64a, t64c, eval_, col, aarr, barr);
    gemm_mfma_kernel<256, 192, 192, 64, 3, true, true, true, false>
        <<<NGB, 256, 0, stream>>>(t64c, t64a, t64b, wp2, conv2_b, aarr, barr, h2, partY);
    bn_finalize_kernel<<<256, 256, 0, stream>>>(partY, bn2_g, bn2_b, aarr + 256, barr + 256, invN, NGB);

    // ---------- Stage C: 3 bottlenecks ----------
    for (int i = 0; i < 3; ++i) {
        float* aA = aarr + (2 + i * 3) * 256; float* bA = barr + (2 + i * 3) * 256;
        float* aB = aarr + (3 + i * 3) * 256; float* bB = barr + (3 + i * 3) * 256;
        float* aC = aarr + (4 + i * 3) * 256; float* bC = barr + (4 + i * 3) * 256;

        // cheb1: K=1, 256->64. For i==0 the input is raw conv2 out -> fuse BN2.
        if (i == 0)
            gemm_mfma_kernel<64, 256, 256, 256, 1, true, true, true, false>
                <<<NGB, 256, 0, stream>>>(h2, nullptr, nullptr, wpc1,
                                          bt_c1b, aarr + 256, barr + 256, t64c, partY);
        else
            gemm_mfma_kernel<64, 256, 256, 256, 1, true, false, true, false>
                <<<NGB, 256, 0, stream>>>(h2, nullptr, nullptr, wpc1 + (size_t)i * 16384,
                                          bt_c1b + i * 64, nullptr, nullptr, t64c, partY);
        bn_finalize_kernel<<<64, 256, 0, stream>>>(partY, btbn1g + i * 64, btbn1b + i * 64, aA, bA, invN, NGB);

        // cheb2: K=3, 64->64; BN1 fused into gathers and x0-staging
        spmm64_kernel<false, true, false><<<NSP64, 256, 0, stream>>>(t64a, t64c, nullptr, eval_, col, aA, bA);
        spmm64_kernel<true, false, true ><<<NSP64, 256, 0, stream>>>(t64b, t64a, t64c, eval_, col, aA, bA);
        gemm_mfma_kernel<64, 192, 192, 64, 3, true, true, true, false>
            <<<NGB, 256, 0, stream>>>(t64c, t64a, t64b, wpc2 + (size_t)i * 12288,
                                      bt_c2b + i * 64, aA, bA, t64d, partY);
        bn_finalize_kernel<<<64, 256, 0, stream>>>(partY, btbn2g + i * 64, btbn2b + i * 64, aB, bB, invN, NGB);

        // cheb3: K=1, 64->256; BN2 fused into x0-staging; stats partial -> t64c
        gemm_mfma_kernel<256, 64, 64, 64, 1, true, true, true, false>
            <<<NGB, 256, 0, stream>>>(t64d, nullptr, nullptr, wpc3 + (size_t)i * 16384,
                                      bt_c3b + i * 256, aB, bB, y3, partC);
        bn_finalize_kernel<<<256, 256, 0, stream>>>(partC, btbn3g + i * 256, btbn3b + i * 256, aC, bC, invN, NGB);

        // residual: h2 = BN3(y3) + base; base is raw conv2 out for i==0 (apply BN2+relu)
        if (i == 0)
            bn_apply_kernel<256, false, true, true><<<NAPP, 256, 0, stream>>>(
                h2, y3, h2, aC, bC, aarr + 256, barr + 256);
        else
            bn_apply_kernel<256, false, true, false><<<NAPP, 256, 0, stream>>>(
                h2, y3, h2, aC, bC, nullptr, nullptr);
    }

    // ---------- Stage D: conv3 (256 -> 8), commuted: out = z0 - z2 + L(z1 + 2*L*z2) ----------
    float* z0 = t64a;
    float* z1 = z0 + (size_t)BV * 8;
    float* z2 = z1 + (size_t)BV * 8;
    float* ee = z2 + (size_t)BV * 8;

    gemm_mfma_kernel<32, 256, 256, 256, 1, false, false, true, true>
        <<<NGB, 256, 0, stream>>>(h2, nullptr, nullptr, wp3, bpack, nullptr, nullptr, z0, nullptr);

    spmm8_kernel<2><<<BV * 8 / 256, 256, 0, stream>>>(ee, z2, z1, nullptr, eval_, col);
    spmm8_kernel<3><<<BV * 8 / 256, 256, 0, stream>>>(out, ee, z0, z2, eval_, col);

    (void)in_sizes; (void)n_in; (void)out_size; (void)ws_size;
}

// Round 12
// 451.187 us; speedup vs baseline: 1.2180x; 1.2156x over previous
//
#include <hip/hip_runtime.h>

static constexpr int NBRS = 21;
static constexpr int Nv   = 12288;
static constexpr int BV   = 4 * Nv;            // 49152 rows
static constexpr float BN_EPS = 1e-5f;

typedef __bf16 bf16x4 __attribute__((ext_vector_type(4)));
typedef __bf16 bf16x8 __attribute__((ext_vector_type(8)));
typedef float  f32x4  __attribute__((ext_vector_type(4)));

// ---------------- SPMM (C=8, scalar). MODE: 0: y=acc; 1: y=2acc-x0;
// 2: y=2acc+x0; 3: y=acc+x0-x1
template<int MODE>
__global__ void spmm8_kernel(float* __restrict__ y, const float* __restrict__ x,
                             const float* __restrict__ x0, const float* __restrict__ x1,
                             const float* __restrict__ val, const int* __restrict__ col)
{
    int idx = blockIdx.x * 256 + threadIdx.x;
    int c = idx % 8;
    int v = (idx / 8) % Nv;
    int b = idx / (8 * Nv);
    int e0 = v * NBRS;
    float acc = 0.f;
    #pragma unroll
    for (int j = 0; j < NBRS; ++j) {
        int u = col[e0 + j];
        acc = fmaf(val[e0 + j], x[((size_t)b * Nv + u) * 8 + c], acc);
    }
    if (MODE == 0)      y[idx] = acc;
    else if (MODE == 1) y[idx] = 2.f * acc - x0[idx];
    else if (MODE == 2) y[idx] = fmaf(2.f, acc, x0[idx]);
    else                y[idx] = acc + x0[idx] - x1[idx];
}

// ---------------- SPMM C=64, float4, one thread per (b,v,q) [round-9 form].
// Optional fused BN+relu on gathered x and/or on x0 (cheb2 variant).
template<bool CHEB2, bool BNG, bool BNX0>
__global__ __launch_bounds__(256)
void spmm64_kernel(float* __restrict__ y, const float* __restrict__ x,
                   const float* __restrict__ x0,
                   const float* __restrict__ val, const int* __restrict__ col,
                   const float* __restrict__ bn_a, const float* __restrict__ bn_b)
{
    int idx = blockIdx.x * 256 + threadIdx.x;   // over BV*16
    int q = idx % 16;
    int v = (idx / 16) % Nv;
    int b = idx / (16 * Nv);
    int e0 = v * NBRS;
    const float4* x4 = (const float4*)x;
    float4 a4, b4;
    if (BNG || (CHEB2 && BNX0)) {
        a4 = ((const float4*)bn_a)[q];
        b4 = ((const float4*)bn_b)[q];
    }
    float4 acc = {0.f, 0.f, 0.f, 0.f};
    #pragma unroll
    for (int j = 0; j < NBRS; ++j) {
        int u = col[e0 + j];
        float a = val[e0 + j];
        float4 xv = x4[(size_t)(b * Nv + u) * 16 + q];
        if (BNG) {
            xv.x = fmaxf(fmaf(xv.x, a4.x, b4.x), 0.f);
            xv.y = fmaxf(fmaf(xv.y, a4.y, b4.y), 0.f);
            xv.z = fmaxf(fmaf(xv.z, a4.z, b4.z), 0.f);
            xv.w = fmaxf(fmaf(xv.w, a4.w, b4.w), 0.f);
        }
        acc.x = fmaf(a, xv.x, acc.x);
        acc.y = fmaf(a, xv.y, acc.y);
        acc.z = fmaf(a, xv.z, acc.z);
        acc.w = fmaf(a, xv.w, acc.w);
    }
    if (CHEB2) {
        float4 pv = ((const float4*)x0)[idx];
        if (BNX0) {
            pv.x = fmaxf(fmaf(pv.x, a4.x, b4.x), 0.f);
            pv.y = fmaxf(fmaf(pv.y, a4.y, b4.y), 0.f);
            pv.z = fmaxf(fmaf(pv.z, a4.z, b4.z), 0.f);
            pv.w = fmaxf(fmaf(pv.w, a4.w, b4.w), 0.f);
        }
        acc.x = 2.f * acc.x - pv.x;
        acc.y = 2.f * acc.y - pv.y;
        acc.z = 2.f * acc.z - pv.z;
        acc.w = 2.f * acc.w - pv.w;
    }
    ((float4*)y)[idx] = acc;
}

// ---------------- conv3 fp32 pre-pack: [3][256][8] -> [256][32] (+ padded bias)
__global__ void pack_conv3_kernel(const float* __restrict__ w, const float* __restrict__ bias,
                                  float* __restrict__ wpack, float* __restrict__ bpack)
{
    int t = blockIdx.x * 256 + threadIdx.x;
    if (t < 256 * 32) {
        int ki = t / 32, c = t % 32;
        int j = c / 8, o = c % 8;
        wpack[t] = (j < 3) ? w[(size_t)j * 2048 + ki * 8 + o] : 0.f;
    }
    if (t < 32) bpack[t] = (t < 8) ? bias[t] : 0.f;
}

// ---------------- mega-pack: all fp32 weights -> fragment-ordered bf16 arena
__global__ __launch_bounds__(256)
void pack_all_kernel(const float* __restrict__ w1, const float* __restrict__ w2,
                     const float* __restrict__ c1, const float* __restrict__ c2,
                     const float* __restrict__ c3, const float* __restrict__ wpk,
                     __bf16* __restrict__ wb)
{
    int t = blockIdx.x * 256 + threadIdx.x;
    if (t >= 194560) return;
    const float* src; int KSRC, FOUT, local;
    if (t < 2048)        { src = w1;  KSRC = 24;  FOUT = 64;  local = t; }
    else if (t < 51200)  { src = w2;  KSRC = 192; FOUT = 256; local = t - 2048; }
    else if (t < 100352) { int i = (t - 51200) / 16384;  src = c1 + (size_t)i * 16384;
                           KSRC = 256; FOUT = 64;  local = (t - 51200) % 16384; }
    else if (t < 137216) { int i = (t - 100352) / 12288; src = c2 + (size_t)i * 12288;
                           KSRC = 192; FOUT = 64;  local = (t - 100352) % 12288; }
    else if (t < 186368) { int i = (t - 137216) / 16384; src = c3 + (size_t)i * 16384;
                           KSRC = 64;  FOUT = 256; local = (t - 137216) % 16384; }
    else                 { src = wpk; KSRC = 256; FOUT = 32;  local = t - 186368; }
    const int j    = local & 7;
    const int lane = (local >> 3) & 63;
    const int rest = local >> 9;
    const int NT = FOUT >> 4;
    const int nt = rest % NT;
    const int ks = rest / NT;
    const int k = ks * 32 + (lane >> 4) * 8 + j;
    const int o = nt * 16 + (lane & 15);
    wb[t] = (k < KSRC) ? (__bf16)src[(size_t)k * FOUT + o] : (__bf16)0.f;
}

// ---------------- MFMA GEMM (round-9 structure)
template<int FOUT, int KFIN, int KPAD, int FIN, int NSRC,
         bool STATS, bool BN0, bool HAS_BIAS, bool PACKOUT>
__global__ __launch_bounds__(256)
void gemm_mfma_kernel(const float* __restrict__ x0, const float* __restrict__ x1,
                      const float* __restrict__ x2,
                      const __bf16* __restrict__ wp, const float* __restrict__ bias,
                      const float* __restrict__ bn_a, const float* __restrict__ bn_b,
                      float* __restrict__ out, float2* __restrict__ partial)
{
    constexpr int NT    = FOUT / 16;
    constexpr int NSTEP = KPAD / 32;
    constexpr bool COLS = (NT % 4 == 0);
    constexpr int NT2   = COLS ? NT / 4 : NT;
    constexpr int LDKB  = KPAD + 8;
    constexpr int LDC   = FOUT + 4;
    constexpr size_t XS_B  = (size_t)64 * LDKB * 2;
    constexpr size_t RPK_B = COLS ? (size_t)16 * LDC * 4 : 0;
    constexpr size_t SMEM  = XS_B > RPK_B ? XS_B : RPK_B;
    __shared__ __align__(16) char smem[SMEM];
    __bf16* xs = (__bf16*)smem;

    const int tid = threadIdx.x;
    const int m0 = blockIdx.x * 64;

    constexpr int NF4 = 64 * (KPAD / 4);
    for (int f = tid; f < NF4; f += 256) {
        const int r  = f / (KPAD / 4);
        const int ki = (f % (KPAD / 4)) * 4;
        bf16x4 h;
        if (KFIN == KPAD || ki < KFIN) {
            const float* src; int i; int kk;
            if constexpr (NSRC == 1) { src = x0; i = ki; kk = 0; }
            else { kk = ki / FIN; i = ki % FIN; src = (kk == 0) ? x0 : (kk == 1 ? x1 : x2); }
            float4 v = *(const float4*)(src + (size_t)(m0 + r) * FIN + i);
            if constexpr (BN0) {
                if (NSRC == 1 || kk == 0) {
                    const float4 a4 = *(const float4*)(bn_a + i);
                    const float4 b4 = *(const float4*)(bn_b + i);
                    v.x = fmaxf(fmaf(v.x, a4.x, b4.x), 0.f);
                    v.y = fmaxf(fmaf(v.y, a4.y, b4.y), 0.f);
                    v.z = fmaxf(fmaf(v.z, a4.z, b4.z), 0.f);
                    v.w = fmaxf(fmaf(v.w, a4.w, b4.w), 0.f);
                }
            }
            h[0] = (__bf16)v.x; h[1] = (__bf16)v.y; h[2] = (__bf16)v.z; h[3] = (__bf16)v.w;
        } else {
            h[0] = (__bf16)0.f; h[1] = (__bf16)0.f; h[2] = (__bf16)0.f; h[3] = (__bf16)0.f;
        }
        *(bf16x4*)(xs + (size_t)r * LDKB + ki) = h;
    }
    __syncthreads();

    const int lane = tid & 63;
    const int wv   = tid >> 6;
    const int lo   = lane & 15;
    const int hi   = lane >> 4;

    if constexpr (COLS) {
        f32x4 acc[4][NT2];
        #pragma unroll
        for (int mr = 0; mr < 4; ++mr)
            #pragma unroll
            for (int n = 0; n < NT2; ++n) acc[mr][n] = (f32x4){0.f, 0.f, 0.f, 0.f};

        #pragma unroll
        for (int ks = 0; ks < NSTEP; ++ks) {
            bf16x8 bfr[NT2];
            #pragma unroll
            for (int n = 0; n < NT2; ++n)
                bfr[n] = *(const bf16x8*)(wp + ((size_t)(ks * NT + wv * NT2 + n) * 64 + lane) * 8);
            bf16x8 afr[4];
            #pragma unroll
            for (int mr = 0; mr < 4; ++mr)
                afr[mr] = *(const bf16x8*)(xs + (size_t)(mr * 16 + lo) * LDKB + ks * 32 + hi * 8);
            #pragma unroll
            for (int n = 0; n < NT2; ++n)
                #pragma unroll
                for (int mr = 0; mr < 4; ++mr)
                    acc[mr][n] = __builtin_amdgcn_mfma_f32_16x16x32_bf16(afr[mr], bfr[n], acc[mr][n], 0, 0, 0);
        }

        #pragma unroll
        for (int n = 0; n < NT2; ++n) {
            const int o = wv * (FOUT / 4) + n * 16 + lo;
            const float bo = HAS_BIAS ? bias[o] : 0.f;
            #pragma unroll
            for (int mr = 0; mr < 4; ++mr)
                #pragma unroll
                for (int j = 0; j < 4; ++j) acc[mr][n][j] += bo;
        }

        if constexpr (STATS) {
            #pragma unroll
            for (int n = 0; n < NT2; ++n) {
                float s = 0.f, q = 0.f;
                #pragma unroll
                for (int mr = 0; mr < 4; ++mr)
                    #pragma unroll
                    for (int j = 0; j < 4; ++j) {
                        const float v = acc[mr][n][j];
                        s += v; q = fmaf(v, v, q);
                    }
                s += __shfl_xor(s, 16); q += __shfl_xor(q, 16);
                s += __shfl_xor(s, 32); q += __shfl_xor(q, 32);
                if (lane < 16) {
                    const int o = wv * (FOUT / 4) + n * 16 + lo;
                    partial[(size_t)o * gridDim.x + blockIdx.x] = make_float2(s, q);
                }
            }
        }

        float* cs = (float*)smem;
        #pragma unroll
        for (int mr = 0; mr < 4; ++mr) {
            __syncthreads();
            #pragma unroll
            for (int n = 0; n < NT2; ++n) {
                const int o = wv * (FOUT / 4) + n * 16 + lo;
                #pragma unroll
                for (int j = 0; j < 4; ++j)
                    cs[(size_t)(hi * 4 + j) * LDC + o] = acc[mr][n][j];
            }
            __syncthreads();
            for (int t = tid; t < 16 * (FOUT / 4); t += 256) {
                const int rr = t / (FOUT / 4);
                const int c4 = (t % (FOUT / 4)) * 4;
                const float4 v = *(const float4*)(cs + (size_t)rr * LDC + c4);
                *(float4*)(out + (size_t)(m0 + mr * 16 + rr) * FOUT + c4) = v;
            }
        }
    } else {
        f32x4 acc[NT];
        #pragma unroll
        for (int nt = 0; nt < NT; ++nt) acc[nt] = (f32x4){0.f, 0.f, 0.f, 0.f};
        const int arow = wv * 16 + lo;
        #pragma unroll
        for (int ks = 0; ks < NSTEP; ++ks) {
            const bf16x8 a = *(const bf16x8*)(xs + (size_t)arow * LDKB + ks * 32 + hi * 8);
            #pragma unroll
            for (int nt = 0; nt < NT; ++nt) {
                const bf16x8 b = *(const bf16x8*)(wp + ((size_t)(ks * NT + nt) * 64 + lane) * 8);
                acc[nt] = __builtin_amdgcn_mfma_f32_16x16x32_bf16(a, b, acc[nt], 0, 0, 0);
            }
        }
        #pragma unroll
        for (int nt = 0; nt < NT; ++nt) {
            const int o = nt * 16 + lo;
            const float bo = HAS_BIAS ? bias[o] : 0.f;
            #pragma unroll
            for (int j = 0; j < 4; ++j) {
                const float v = acc[nt][j] + bo;
                const int m = m0 + wv * 16 + hi * 4 + j;
                if constexpr (PACKOUT) {
                    const int zj = o >> 3;
                    if (zj < 3) out[((size_t)zj * BV + m) * 8 + (o & 7)] = v;
                } else {
                    out[(size_t)m * FOUT + o] = v;
                }
            }
        }
    }
}

// ---------------- BN finalize: one block per channel, coalesced over [C][nblk]
__global__ __launch_bounds__(256)
void bn_finalize_kernel(const float2* __restrict__ partial,
                        const float* __restrict__ g, const float* __restrict__ b,
                        float* __restrict__ a_out, float* __restrict__ b_out,
                        float invN, int nblk)
{
    __shared__ float2 red[4];
    const int c = blockIdx.x;
    const float2* p = partial + (size_t)c * nblk;
    float s = 0.f, ss = 0.f;
    for (int k = threadIdx.x; k < nblk; k += 256) {
        const float2 v = p[k];
        s += v.x; ss += v.y;
    }
    #pragma unroll
    for (int off = 32; off > 0; off >>= 1) {
        s  += __shfl_down(s, off);
        ss += __shfl_down(ss, off);
    }
    if ((threadIdx.x & 63) == 0) red[threadIdx.x >> 6] = make_float2(s, ss);
    __syncthreads();
    if (threadIdx.x == 0) {
        float ts = 0.f, tq = 0.f;
        #pragma unroll
        for (int i = 0; i < 4; ++i) { ts += red[i].x; tq += red[i].y; }
        const float m = ts * invN;
        const float var = tq * invN - m * m;
        const float a = g[c] * rsqrtf(var + BN_EPS);
        a_out[c] = a;
        b_out[c] = b[c] - m * a;
    }
}

// ---------------- BN apply (float4). BASEBN: base gets relu(BN2(base)) first.
template<int C, bool RELU, bool ADD, bool BASEBN>
__global__ __launch_bounds__(256)
void bn_apply_kernel(float* __restrict__ out, const float* __restrict__ x,
                     const float* __restrict__ base,
                     const float* __restrict__ bn_a, const float* __restrict__ bn_b,
                     const float* __restrict__ bn_a2, const float* __restrict__ bn_b2)
{
    int i = blockIdx.x * 256 + threadIdx.x;   // float4 index
    float4 v = ((const float4*)x)[i];
    int c0 = (i * 4) % C;
    float4 a4 = *reinterpret_cast<const float4*>(bn_a + c0);
    float4 b4 = *reinterpret_cast<const float4*>(bn_b + c0);
    float4 r;
    r.x = fmaf(v.x, a4.x, b4.x);
    r.y = fmaf(v.y, a4.y, b4.y);
    r.z = fmaf(v.z, a4.z, b4.z);
    r.w = fmaf(v.w, a4.w, b4.w);
    if (ADD) {
        float4 bvv = ((const float4*)base)[i];
        if (BASEBN) {
            float4 p4 = *reinterpret_cast<const float4*>(bn_a2 + c0);
            float4 q4 = *reinterpret_cast<const float4*>(bn_b2 + c0);
            bvv.x = fmaxf(fmaf(bvv.x, p4.x, q4.x), 0.f);
            bvv.y = fmaxf(fmaf(bvv.y, p4.y, q4.y), 0.f);
            bvv.z = fmaxf(fmaf(bvv.z, p4.z, q4.z), 0.f);
            bvv.w = fmaxf(fmaf(bvv.w, p4.w, q4.w), 0.f);
        }
        r.x += bvv.x; r.y += bvv.y; r.z += bvv.z; r.w += bvv.w;
    }
    if (RELU) {
        r.x = fmaxf(r.x, 0.f); r.y = fmaxf(r.y, 0.f);
        r.z = fmaxf(r.z, 0.f); r.w = fmaxf(r.w, 0.f);
    }
    ((float4*)out)[i] = r;
}

extern "C" void kernel_launch(void* const* d_in, const int* in_sizes, int n_in,
                              void* d_out, int out_size, void* d_ws, size_t ws_size,
                              hipStream_t stream)
{
    const float* x       = (const float*)d_in[0];
    const int*   col     = (const int*)  d_in[2];
    const float* eval_   = (const float*)d_in[3];
    const float* conv1_w = (const float*)d_in[4];
    const float* conv1_b = (const float*)d_in[5];
    const float* bn1_g   = (const float*)d_in[6];
    const float* bn1_b   = (const float*)d_in[7];
    const float* conv2_w = (const float*)d_in[8];
    const float* conv2_b = (const float*)d_in[9];
    const float* bn2_g   = (const float*)d_in[10];
    const float* bn2_b   = (const float*)d_in[11];
    const float* bt_c1w  = (const float*)d_in[12];
    const float* bt_c1b  = (const float*)d_in[13];
    const float* bt_c2w  = (const float*)d_in[14];
    const float* bt_c2b  = (const float*)d_in[15];
    const float* bt_c3w  = (const float*)d_in[16];
    const float* bt_c3b  = (const float*)d_in[17];
    const float* btbn1g  = (const float*)d_in[18];
    const float* btbn1b  = (const float*)d_in[19];
    const float* btbn2g  = (const float*)d_in[20];
    const float* btbn2b  = (const float*)d_in[21];
    const float* btbn3g  = (const float*)d_in[22];
    const float* btbn3b  = (const float*)d_in[23];
    const float* conv3_w = (const float*)d_in[24];
    const float* conv3_b = (const float*)d_in[25];
    float* out = (float*)d_out;

    float* ws = (float*)d_ws;
    float* h2    = ws;                         // BV*256 (raw conv2 out, then residual trunk)
    float* y3    = h2 + (size_t)BV * 256;      // BV*256 (aliased as stats partial)
    float* t64a  = y3 + (size_t)BV * 256;      // BV*64
    float* t64b  = t64a + (size_t)BV * 64;     // BV*64
    float* t64c  = t64b + (size_t)BV * 64;     // BV*64
    float* t64d  = t64c + (size_t)BV * 64;     // BV*64
    float* aarr  = t64d + (size_t)BV * 64;     // 11*256
    float* barr  = aarr + 11 * 256;            // 11*256
    float* wpack = barr + 11 * 256;            // 256*32 fp32 (conv3 packed)
    float* bpack = wpack + 256 * 32;           // 32
    __bf16* wb   = (__bf16*)(bpack + 32);      // bf16 weight arena (contiguous regions)
    __bf16* wp1  = wb;                         // 2048
    __bf16* wp2  = wp1 + 2048;                 // 49152
    __bf16* wpc1 = wp2 + 49152;                // 49152
    __bf16* wpc2 = wpc1 + 49152;               // 36864
    __bf16* wpc3 = wpc2 + 36864;               // 49152
    __bf16* wp3  = wpc3 + 49152;               // 8192
    float2* partY = (float2*)y3;
    float2* partC = (float2*)t64c;

    const float invN = 1.f / (float)BV;
    const int NGB  = BV / 64;                  // 768 MFMA GEMM blocks
    const int NAPP = BV / 4;                   // C=256 bn_apply blocks
    const int NSP64 = BV * 16 / 256;           // 3072 spmm64 blocks (round-9 grid)

    // ---------- packing: 2 launches ----------
    pack_conv3_kernel<<<32, 256, 0, stream>>>(conv3_w, conv3_b, wpack, bpack);
    pack_all_kernel<<<760, 256, 0, stream>>>(conv1_w, conv2_w, bt_c1w, bt_c2w, bt_c3w, wpack, wb);

    // ---------- Stage A: conv1 (8 -> 64), K=3 ----------
    spmm8_kernel<0><<<BV * 8 / 256, 256, 0, stream>>>(t64a, x, nullptr, nullptr, eval_, col);
    spmm8_kernel<1><<<BV * 8 / 256, 256, 0, stream>>>(t64b, t64a, x, nullptr, eval_, col);
    gemm_mfma_kernel<64, 24, 32, 8, 3, true, false, true, false>
        <<<NGB, 256, 0, stream>>>(x, t64a, t64b, wp1, conv1_b, nullptr, nullptr, t64c, partY);
    bn_finalize_kernel<<<64, 256, 0, stream>>>(partY, bn1_g, bn1_b, aarr, barr, invN, NGB);

    // ---------- Stage B: conv2 (64 -> 256), K=3; h2 stays RAW (BN2 fused at readers)
    spmm64_kernel<false, true, false><<<NSP64, 256, 0, stream>>>(t64a, t64c, nullptr, eval_, col, aarr, barr);
    spmm64_kernel<true, false, true ><<<NSP64, 256, 0, stream>>>(t64b, t64a, t64c, eval_, col, aarr, barr);
    gemm_mfma_kernel<256, 192, 192, 64, 3, true, true, true, false>
        <<<NGB, 256, 0, stream>>>(t64c, t64a, t64b, wp2, conv2_b, aarr, barr, h2, partY);
    bn_finalize_kernel<<<256, 256, 0, stream>>>(partY, bn2_g, bn2_b, aarr + 256, barr + 256, invN, NGB);

    // ---------- Stage C: 3 bottlenecks ----------
    for (int i = 0; i < 3; ++i) {
        float* aA = aarr + (2 + i * 3) * 256; float* bA = barr + (2 + i * 3) * 256;
        float* aB = aarr + (3 + i * 3) * 256; float* bB = barr + (3 + i * 3) * 256;
        float* aC = aarr + (4 + i * 3) * 256; float* bC = barr + (4 + i * 3) * 256;

        // cheb1: K=1, 256->64. For i==0 the input is raw conv2 out -> fuse BN2.
        if (i == 0)
            gemm_mfma_kernel<64, 256, 256, 256, 1, true, true, true, false>
                <<<NGB, 256, 0, stream>>>(h2, nullptr, nullptr, wpc1,
                                          bt_c1b, aarr + 256, barr + 256, t64c, partY);
        else
            gemm_mfma_kernel<64, 256, 256, 256, 1, true, false, true, false>
                <<<NGB, 256, 0, stream>>>(h2, nullptr, nullptr, wpc1 + (size_t)i * 16384,
                                          bt_c1b + i * 64, nullptr, nullptr, t64c, partY);
        bn_finalize_kernel<<<64, 256, 0, stream>>>(partY, btbn1g + i * 64, btbn1b + i * 64, aA, bA, invN, NGB);

        // cheb2: K=3, 64->64; BN1 fused into gathers and x0-staging
        spmm64_kernel<false, true, false><<<NSP64, 256, 0, stream>>>(t64a, t64c, nullptr, eval_, col, aA, bA);
        spmm64_kernel<true, false, true ><<<NSP64, 256, 0, stream>>>(t64b, t64a, t64c, eval_, col, aA, bA);
        gemm_mfma_kernel<64, 192, 192, 64, 3, true, true, true, false>
            <<<NGB, 256, 0, stream>>>(t64c, t64a, t64b, wpc2 + (size_t)i * 12288,
                                      bt_c2b + i * 64, aA, bA, t64d, partY);
        bn_finalize_kernel<<<64, 256, 0, stream>>>(partY, btbn2g + i * 64, btbn2b + i * 64, aB, bB, invN, NGB);

        // cheb3: K=1, 64->256; BN2 fused into x0-staging; stats partial -> t64c
        gemm_mfma_kernel<256, 64, 64, 64, 1, true, true, true, false>
            <<<NGB, 256, 0, stream>>>(t64d, nullptr, nullptr, wpc3 + (size_t)i * 16384,
                                      bt_c3b + i * 256, aB, bB, y3, partC);
        bn_finalize_kernel<<<256, 256, 0, stream>>>(partC, btbn3g + i * 256, btbn3b + i * 256, aC, bC, invN, NGB);

        // residual: h2 = BN3(y3) + base; base is raw conv2 out for i==0 (apply BN2+relu)
        if (i == 0)
            bn_apply_kernel<256, false, true, true><<<NAPP, 256, 0, stream>>>(
                h2, y3, h2, aC, bC, aarr + 256, barr + 256);
        else
            bn_apply_kernel<256, false, true, false><<<NAPP, 256, 0, stream>>>(
                h2, y3, h2, aC, bC, nullptr, nullptr);
    }

    // ---------- Stage D: conv3 (256 -> 8), commuted: out = z0 - z2 + L(z1 + 2*L*z2) ----------
    float* z0 = t64a;
    float* z1 = z0 + (size_t)BV * 8;
    float* z2 = z1 + (size_t)BV * 8;
    float* ee = z2 + (size_t)BV * 8;

    gemm_mfma_kernel<32, 256, 256, 256, 1, false, false, true, true>
        <<<NGB, 256, 0, stream>>>(h2, nullptr, nullptr, wp3, bpack, nullptr, nullptr, z0, nullptr);

    spmm8_kernel<2><<<BV * 8 / 256, 256, 0, stream>>>(ee, z2, z1, nullptr, eval_, col);
    spmm8_kernel<3><<<BV * 8 / 256, 256, 0, stream>>>(out, ee, z0, z2, eval_, col);

    (void)in_sizes; (void)n_in; (void)out_size; (void)ws_size;
}

// Round 13
// 449.470 us; speedup vs baseline: 1.2227x; 1.0038x over previous
//
#include <hip/hip_runtime.h>

static constexpr int NBRS = 21;
static constexpr int Nv   = 12288;
static constexpr int BV   = 4 * Nv;            // 49152 rows
static constexpr float BN_EPS = 1e-5f;

typedef __bf16 bf16x4 __attribute__((ext_vector_type(4)));
typedef __bf16 bf16x8 __attribute__((ext_vector_type(8)));
typedef float  f32x4  __attribute__((ext_vector_type(4)));

// ---------------- SPMM (C=8, scalar). MODE: 0: y=acc; 1: y=2acc-x0;
// 2: y=2acc+x0; 3: y=acc+x0-x1
template<int MODE>
__global__ void spmm8_kernel(float* __restrict__ y, const float* __restrict__ x,
                             const float* __restrict__ x0, const float* __restrict__ x1,
                             const float* __restrict__ val, const int* __restrict__ col)
{
    int idx = blockIdx.x * 256 + threadIdx.x;
    int c = idx % 8;
    int v = (idx / 8) % Nv;
    int b = idx / (8 * Nv);
    int e0 = v * NBRS;
    float acc = 0.f;
    #pragma unroll
    for (int j = 0; j < NBRS; ++j) {
        int u = col[e0 + j];
        acc = fmaf(val[e0 + j], x[((size_t)b * Nv + u) * 8 + c], acc);
    }
    if (MODE == 0)      y[idx] = acc;
    else if (MODE == 1) y[idx] = 2.f * acc - x0[idx];
    else if (MODE == 2) y[idx] = fmaf(2.f, acc, x0[idx]);
    else                y[idx] = acc + x0[idx] - x1[idx];
}

// ---------------- SPMM C=64, float4, one thread per (b,v,q) [round-9 form].
// Optional fused BN+relu on gathered x and/or on x0 (cheb2 variant).
template<bool CHEB2, bool BNG, bool BNX0>
__global__ __launch_bounds__(256)
void spmm64_kernel(float* __restrict__ y, const float* __restrict__ x,
                   const float* __restrict__ x0,
                   const float* __restrict__ val, const int* __restrict__ col,
                   const float* __restrict__ bn_a, const float* __restrict__ bn_b)
{
    int idx = blockIdx.x * 256 + threadIdx.x;   // over BV*16
    int q = idx % 16;
    int v = (idx / 16) % Nv;
    int b = idx / (16 * Nv);
    int e0 = v * NBRS;
    const float4* x4 = (const float4*)x;
    float4 a4, b4;
    if (BNG || (CHEB2 && BNX0)) {
        a4 = ((const float4*)bn_a)[q];
        b4 = ((const float4*)bn_b)[q];
    }
    float4 acc = {0.f, 0.f, 0.f, 0.f};
    #pragma unroll
    for (int j = 0; j < NBRS; ++j) {
        int u = col[e0 + j];
        float a = val[e0 + j];
        float4 xv = x4[(size_t)(b * Nv + u) * 16 + q];
        if (BNG) {
            xv.x = fmaxf(fmaf(xv.x, a4.x, b4.x), 0.f);
            xv.y = fmaxf(fmaf(xv.y, a4.y, b4.y), 0.f);
            xv.z = fmaxf(fmaf(xv.z, a4.z, b4.z), 0.f);
            xv.w = fmaxf(fmaf(xv.w, a4.w, b4.w), 0.f);
        }
        acc.x = fmaf(a, xv.x, acc.x);
        acc.y = fmaf(a, xv.y, acc.y);
        acc.z = fmaf(a, xv.z, acc.z);
        acc.w = fmaf(a, xv.w, acc.w);
    }
    if (CHEB2) {
        float4 pv = ((const float4*)x0)[idx];
        if (BNX0) {
            pv.x = fmaxf(fmaf(pv.x, a4.x, b4.x), 0.f);
            pv.y = fmaxf(fmaf(pv.y, a4.y, b4.y), 0.f);
            pv.z = fmaxf(fmaf(pv.z, a4.z, b4.z), 0.f);
            pv.w = fmaxf(fmaf(pv.w, a4.w, b4.w), 0.f);
        }
        acc.x = 2.f * acc.x - pv.x;
        acc.y = 2.f * acc.y - pv.y;
        acc.z = 2.f * acc.z - pv.z;
        acc.w = 2.f * acc.w - pv.w;
    }
    ((float4*)y)[idx] = acc;
}

// ---------------- conv3 fp32 pre-pack: [3][256][8] -> [256][32] (+ padded bias)
__global__ void pack_conv3_kernel(const float* __restrict__ w, const float* __restrict__ bias,
                                  float* __restrict__ wpack, float* __restrict__ bpack)
{
    int t = blockIdx.x * 256 + threadIdx.x;
    if (t < 256 * 32) {
        int ki = t / 32, c = t % 32;
        int j = c / 8, o = c % 8;
        wpack[t] = (j < 3) ? w[(size_t)j * 2048 + ki * 8 + o] : 0.f;
    }
    if (t < 32) bpack[t] = (t < 8) ? bias[t] : 0.f;
}

// ---------------- mega-pack: all fp32 weights -> fragment-ordered bf16 arena
__global__ __launch_bounds__(256)
void pack_all_kernel(const float* __restrict__ w1, const float* __restrict__ w2,
                     const float* __restrict__ c1, const float* __restrict__ c2,
                     const float* __restrict__ c3, const float* __restrict__ wpk,
                     __bf16* __restrict__ wb)
{
    int t = blockIdx.x * 256 + threadIdx.x;
    if (t >= 194560) return;
    const float* src; int KSRC, FOUT, local;
    if (t < 2048)        { src = w1;  KSRC = 24;  FOUT = 64;  local = t; }
    else if (t < 51200)  { src = w2;  KSRC = 192; FOUT = 256; local = t - 2048; }
    else if (t < 100352) { int i = (t - 51200) / 16384;  src = c1 + (size_t)i * 16384;
                           KSRC = 256; FOUT = 64;  local = (t - 51200) % 16384; }
    else if (t < 137216) { int i = (t - 100352) / 12288; src = c2 + (size_t)i * 12288;
                           KSRC = 192; FOUT = 64;  local = (t - 100352) % 12288; }
    else if (t < 186368) { int i = (t - 137216) / 16384; src = c3 + (size_t)i * 16384;
                           KSRC = 64;  FOUT = 256; local = (t - 137216) % 16384; }
    else                 { src = wpk; KSRC = 256; FOUT = 32;  local = t - 186368; }
    const int j    = local & 7;
    const int lane = (local >> 3) & 63;
    const int rest = local >> 9;
    const int NT = FOUT >> 4;
    const int nt = rest % NT;
    const int ks = rest / NT;
    const int k = ks * 32 + (lane >> 4) * 8 + j;
    const int o = nt * 16 + (lane & 15);
    wb[t] = (k < KSRC) ? (__bf16)src[(size_t)k * FOUT + o] : (__bf16)0.f;
}

// ---------------- MFMA GEMM (round-9 structure)
template<int FOUT, int KFIN, int KPAD, int FIN, int NSRC,
         bool STATS, bool BN0, bool HAS_BIAS, bool PACKOUT>
__global__ __launch_bounds__(256)
void gemm_mfma_kernel(const float* __restrict__ x0, const float* __restrict__ x1,
                      const float* __restrict__ x2,
                      const __bf16* __restrict__ wp, const float* __restrict__ bias,
                      const float* __restrict__ bn_a, const float* __restrict__ bn_b,
                      float* __restrict__ out, float2* __restrict__ partial)
{
    constexpr int NT    = FOUT / 16;
    constexpr int NSTEP = KPAD / 32;
    constexpr bool COLS = (NT % 4 == 0);
    constexpr int NT2   = COLS ? NT / 4 : NT;
    constexpr int LDKB  = KPAD + 8;
    constexpr int LDC   = FOUT + 4;
    constexpr size_t XS_B  = (size_t)64 * LDKB * 2;
    constexpr size_t RPK_B = COLS ? (size_t)16 * LDC * 4 : 0;
    constexpr size_t SMEM  = XS_B > RPK_B ? XS_B : RPK_B;
    __shared__ __align__(16) char smem[SMEM];
    __bf16* xs = (__bf16*)smem;

    const int tid = threadIdx.x;
    const int m0 = blockIdx.x * 64;

    constexpr int NF4 = 64 * (KPAD / 4);
    for (int f = tid; f < NF4; f += 256) {
        const int r  = f / (KPAD / 4);
        const int ki = (f % (KPAD / 4)) * 4;
        bf16x4 h;
        if (KFIN == KPAD || ki < KFIN) {
            const float* src; int i; int kk;
            if constexpr (NSRC == 1) { src = x0; i = ki; kk = 0; }
            else { kk = ki / FIN; i = ki % FIN; src = (kk == 0) ? x0 : (kk == 1 ? x1 : x2); }
            float4 v = *(const float4*)(src + (size_t)(m0 + r) * FIN + i);
            if constexpr (BN0) {
                if (NSRC == 1 || kk == 0) {
                    const float4 a4 = *(const float4*)(bn_a + i);
                    const float4 b4 = *(const float4*)(bn_b + i);
                    v.x = fmaxf(fmaf(v.x, a4.x, b4.x), 0.f);
                    v.y = fmaxf(fmaf(v.y, a4.y, b4.y), 0.f);
                    v.z = fmaxf(fmaf(v.z, a4.z, b4.z), 0.f);
                    v.w = fmaxf(fmaf(v.w, a4.w, b4.w), 0.f);
                }
            }
            h[0] = (__bf16)v.x; h[1] = (__bf16)v.y; h[2] = (__bf16)v.z; h[3] = (__bf16)v.w;
        } else {
            h[0] = (__bf16)0.f; h[1] = (__bf16)0.f; h[2] = (__bf16)0.f; h[3] = (__bf16)0.f;
        }
        *(bf16x4*)(xs + (size_t)r * LDKB + ki) = h;
    }
    __syncthreads();

    const int lane = tid & 63;
    const int wv   = tid >> 6;
    const int lo   = lane & 15;
    const int hi   = lane >> 4;

    if constexpr (COLS) {
        f32x4 acc[4][NT2];
        #pragma unroll
        for (int mr = 0; mr < 4; ++mr)
            #pragma unroll
            for (int n = 0; n < NT2; ++n) acc[mr][n] = (f32x4){0.f, 0.f, 0.f, 0.f};

        #pragma unroll
        for (int ks = 0; ks < NSTEP; ++ks) {
            bf16x8 bfr[NT2];
            #pragma unroll
            for (int n = 0; n < NT2; ++n)
                bfr[n] = *(const bf16x8*)(wp + ((size_t)(ks * NT + wv * NT2 + n) * 64 + lane) * 8);
            bf16x8 afr[4];
            #pragma unroll
            for (int mr = 0; mr < 4; ++mr)
                afr[mr] = *(const bf16x8*)(xs + (size_t)(mr * 16 + lo) * LDKB + ks * 32 + hi * 8);
            #pragma unroll
            for (int n = 0; n < NT2; ++n)
                #pragma unroll
                for (int mr = 0; mr < 4; ++mr)
                    acc[mr][n] = __builtin_amdgcn_mfma_f32_16x16x32_bf16(afr[mr], bfr[n], acc[mr][n], 0, 0, 0);
        }

        #pragma unroll
        for (int n = 0; n < NT2; ++n) {
            const int o = wv * (FOUT / 4) + n * 16 + lo;
            const float bo = HAS_BIAS ? bias[o] : 0.f;
            #pragma unroll
            for (int mr = 0; mr < 4; ++mr)
                #pragma unroll
                for (int j = 0; j < 4; ++j) acc[mr][n][j] += bo;
        }

        if constexpr (STATS) {
            #pragma unroll
            for (int n = 0; n < NT2; ++n) {
                float s = 0.f, q = 0.f;
                #pragma unroll
                for (int mr = 0; mr < 4; ++mr)
                    #pragma unroll
                    for (int j = 0; j < 4; ++j) {
                        const float v = acc[mr][n][j];
                        s += v; q = fmaf(v, v, q);
                    }
                s += __shfl_xor(s, 16); q += __shfl_xor(q, 16);
                s += __shfl_xor(s, 32); q += __shfl_xor(q, 32);
                if (lane < 16) {
                    const int o = wv * (FOUT / 4) + n * 16 + lo;
                    partial[(size_t)o * gridDim.x + blockIdx.x] = make_float2(s, q);
                }
            }
        }

        float* cs = (float*)smem;
        #pragma unroll
        for (int mr = 0; mr < 4; ++mr) {
            __syncthreads();
            #pragma unroll
            for (int n = 0; n < NT2; ++n) {
                const int o = wv * (FOUT / 4) + n * 16 + lo;
                #pragma unroll
                for (int j = 0; j < 4; ++j)
                    cs[(size_t)(hi * 4 + j) * LDC + o] = acc[mr][n][j];
            }
            __syncthreads();
            for (int t = tid; t < 16 * (FOUT / 4); t += 256) {
                const int rr = t / (FOUT / 4);
                const int c4 = (t % (FOUT / 4)) * 4;
                const float4 v = *(const float4*)(cs + (size_t)rr * LDC + c4);
                *(float4*)(out + (size_t)(m0 + mr * 16 + rr) * FOUT + c4) = v;
            }
        }
    } else {
        f32x4 acc[NT];
        #pragma unroll
        for (int nt = 0; nt < NT; ++nt) acc[nt] = (f32x4){0.f, 0.f, 0.f, 0.f};
        const int arow = wv * 16 + lo;
        #pragma unroll
        for (int ks = 0; ks < NSTEP; ++ks) {
            const bf16x8 a = *(const bf16x8*)(xs + (size_t)arow * LDKB + ks * 32 + hi * 8);
            #pragma unroll
            for (int nt = 0; nt < NT; ++nt) {
                const bf16x8 b = *(const bf16x8*)(wp + ((size_t)(ks * NT + nt) * 64 + lane) * 8);
                acc[nt] = __builtin_amdgcn_mfma_f32_16x16x32_bf16(a, b, acc[nt], 0, 0, 0);
            }
        }
        #pragma unroll
        for (int nt = 0; nt < NT; ++nt) {
            const int o = nt * 16 + lo;
            const float bo = HAS_BIAS ? bias[o] : 0.f;
            #pragma unroll
            for (int j = 0; j < 4; ++j) {
                const float v = acc[nt][j] + bo;
                const int m = m0 + wv * 16 + hi * 4 + j;
                if constexpr (PACKOUT) {
                    const int zj = o >> 3;
                    if (zj < 3) out[((size_t)zj * BV + m) * 8 + (o & 7)] = v;
                } else {
                    out[(size_t)m * FOUT + o] = v;
                }
            }
        }
    }
}

// ---------------- BN finalize: one block per channel, coalesced over [C][nblk]
__global__ __launch_bounds__(256)
void bn_finalize_kernel(const float2* __restrict__ partial,
                        const float* __restrict__ g, const float* __restrict__ b,
                        float* __restrict__ a_out, float* __restrict__ b_out,
                        float invN, int nblk)
{
    __shared__ float2 red[4];
    const int c = blockIdx.x;
    const float2* p = partial + (size_t)c * nblk;
    float s = 0.f, ss = 0.f;
    for (int k = threadIdx.x; k < nblk; k += 256) {
        const float2 v = p[k];
        s += v.x; ss += v.y;
    }
    #pragma unroll
    for (int off = 32; off > 0; off >>= 1) {
        s  += __shfl_down(s, off);
        ss += __shfl_down(ss, off);
    }
    if ((threadIdx.x & 63) == 0) red[threadIdx.x >> 6] = make_float2(s, ss);
    __syncthreads();
    if (threadIdx.x == 0) {
        float ts = 0.f, tq = 0.f;
        #pragma unroll
        for (int i = 0; i < 4; ++i) { ts += red[i].x; tq += red[i].y; }
        const float m = ts * invN;
        const float var = tq * invN - m * m;
        const float a = g[c] * rsqrtf(var + BN_EPS);
        a_out[c] = a;
        b_out[c] = b[c] - m * a;
    }
}

// ---------------- BN apply (float4). BASEBN: base gets relu(BN2(base)) first.
template<int C, bool RELU, bool ADD, bool BASEBN>
__global__ __launch_bounds__(256)
void bn_apply_kernel(float* __restrict__ out, const float* __restrict__ x,
                     const float* __restrict__ base,
                     const float* __restrict__ bn_a, const float* __restrict__ bn_b,
                     const float* __restrict__ bn_a2, const float* __restrict__ bn_b2)
{
    int i = blockIdx.x * 256 + threadIdx.x;   // float4 index
    float4 v = ((const float4*)x)[i];
    int c0 = (i * 4) % C;
    float4 a4 = *reinterpret_cast<const float4*>(bn_a + c0);
    float4 b4 = *reinterpret_cast<const float4*>(bn_b + c0);
    float4 r;
    r.x = fmaf(v.x, a4.x, b4.x);
    r.y = fmaf(v.y, a4.y, b4.y);
    r.z = fmaf(v.z, a4.z, b4.z);
    r.w = fmaf(v.w, a4.w, b4.w);
    if (ADD) {
        float4 bvv = ((const float4*)base)[i];
        if (BASEBN) {
            float4 p4 = *reinterpret_cast<const float4*>(bn_a2 + c0);
            float4 q4 = *reinterpret_cast<const float4*>(bn_b2 + c0);
            bvv.x = fmaxf(fmaf(bvv.x, p4.x, q4.x), 0.f);
            bvv.y = fmaxf(fmaf(bvv.y, p4.y, q4.y), 0.f);
            bvv.z = fmaxf(fmaf(bvv.z, p4.z, q4.z), 0.f);
            bvv.w = fmaxf(fmaf(bvv.w, p4.w, q4.w), 0.f);
        }
        r.x += bvv.x; r.y += bvv.y; r.z += bvv.z; r.w += bvv.w;
    }
    if (RELU) {
        r.x = fmaxf(r.x, 0.f); r.y = fmaxf(r.y, 0.f);
        r.z = fmaxf(r.z, 0.f); r.w = fmaxf(r.w, 0.f);
    }
    ((float4*)out)[i] = r;
}

extern "C" void kernel_launch(void* const* d_in, const int* in_sizes, int n_in,
                              void* d_out, int out_size, void* d_ws, size_t ws_size,
                              hipStream_t stream)
{
    const float* x       = (const float*)d_in[0];
    const int*   col     = (const int*)  d_in[2];
    const float* eval_   = (const float*)d_in[3];
    const float* conv1_w = (const float*)d_in[4];
    const float* conv1_b = (const float*)d_in[5];
    const float* bn1_g   = (const float*)d_in[6];
    const float* bn1_b   = (const float*)d_in[7];
    const float* conv2_w = (const float*)d_in[8];
    const float* conv2_b = (const float*)d_in[9];
    const float* bn2_g   = (const float*)d_in[10];
    const float* bn2_b   = (const float*)d_in[11];
    const float* bt_c1w  = (const float*)d_in[12];
    const float* bt_c1b  = (const float*)d_in[13];
    const float* bt_c2w  = (const float*)d_in[14];
    const float* bt_c2b  = (const float*)d_in[15];
    const float* bt_c3w  = (const float*)d_in[16];
    const float* bt_c3b  = (const float*)d_in[17];
    const float* btbn1g  = (const float*)d_in[18];
    const float* btbn1b  = (const float*)d_in[19];
    const float* btbn2g  = (const float*)d_in[20];
    const float* btbn2b  = (const float*)d_in[21];
    const float* btbn3g  = (const float*)d_in[22];
    const float* btbn3b  = (const float*)d_in[23];
    const float* conv3_w = (const float*)d_in[24];
    const float* conv3_b = (const float*)d_in[25];
    float* out = (float*)d_out;

    float* ws = (float*)d_ws;
    float* h2    = ws;                         // BV*256 (raw conv2 out, then residual trunk)
    float* y3    = h2 + (size_t)BV * 256;      // BV*256 (aliased as stats partial)
    float* t64a  = y3 + (size_t)BV * 256;      // BV*64
    float* t64b  = t64a + (size_t)BV * 64;     // BV*64
    float* t64c  = t64b + (size_t)BV * 64;     // BV*64
    float* t64d  = t64c + (size_t)BV * 64;     // BV*64
    float* aarr  = t64d + (size_t)BV * 64;     // 11*256
    float* barr  = aarr + 11 * 256;            // 11*256
    float* wpack = barr + 11 * 256;            // 256*32 fp32 (conv3 packed)
    float* bpack = wpack + 256 * 32;           // 32
    __bf16* wb   = (__bf16*)(bpack + 32);      // bf16 weight arena (contiguous regions)
    __bf16* wp1  = wb;                         // 2048
    __bf16* wp2  = wp1 + 2048;                 // 49152
    __bf16* wpc1 = wp2 + 49152;                // 49152
    __bf16* wpc2 = wpc1 + 49152;               // 36864
    __bf16* wpc3 = wpc2 + 36864;               // 49152
    __bf16* wp3  = wpc3 + 49152;               // 8192
    float2* partY = (float2*)y3;
    float2* partC = (float2*)t64c;

    const float invN = 1.f / (float)BV;
    const int NGB  = BV / 64;                  // 768 MFMA GEMM blocks
    const int NAPP = BV / 4;                   // C=256 bn_apply blocks
    const int NSP64 = BV * 16 / 256;           // 3072 spmm64 blocks (round-9 grid)

    // ---------- packing: 2 launches ----------
    pack_conv3_kernel<<<32, 256, 0, stream>>>(conv3_w, conv3_b, wpack, bpack);
    pack_all_kernel<<<760, 256, 0, stream>>>(conv1_w, conv2_w, bt_c1w, bt_c2w, bt_c3w, wpack, wb);

    // ---------- Stage A: conv1 (8 -> 64), K=3 ----------
    spmm8_kernel<0><<<BV * 8 / 256, 256, 0, stream>>>(t64a, x, nullptr, nullptr, eval_, col);
    spmm8_kernel<1><<<BV * 8 / 256, 256, 0, stream>>>(t64b, t64a, x, nullptr, eval_, col);
    gemm_mfma_kernel<64, 24, 32, 8, 3, true, false, true, false>
        <<<NGB, 256, 0, stream>>>(x, t64a, t64b, wp1, conv1_b, nullptr, nullptr, t64c, partY);
    bn_finalize_kernel<<<64, 256, 0, stream>>>(partY, bn1_g, bn1_b, aarr, barr, invN, NGB);

    // ---------- Stage B: conv2 (64 -> 256), K=3; h2 stays RAW (BN2 fused at readers)
    spmm64_kernel<false, true, false><<<NSP64, 256, 0, stream>>>(t64a, t64c, nullptr, eval_, col, aarr, barr);
    spmm64_kernel<true, false, true ><<<NSP64, 256, 0, stream>>>(t64b, t64a, t64c, eval_, col, aarr, barr);
    gemm_mfma_kernel<256, 192, 192, 64, 3, true, true, true, false>
        <<<NGB, 256, 0, stream>>>(t64c, t64a, t64b, wp2, conv2_b, aarr, barr, h2, partY);
    bn_finalize_kernel<<<256, 256, 0, stream>>>(partY, bn2_g, bn2_b, aarr + 256, barr + 256, invN, NGB);

    // ---------- Stage C: 3 bottlenecks ----------
    for (int i = 0; i < 3; ++i) {
        float* aA = aarr + (2 + i * 3) * 256; float* bA = barr + (2 + i * 3) * 256;
        float* aB = aarr + (3 + i * 3) * 256; float* bB = barr + (3 + i * 3) * 256;
        float* aC = aarr + (4 + i * 3) * 256; float* bC = barr + (4 + i * 3) * 256;

        // cheb1: K=1, 256->64. For i==0 the input is raw conv2 out -> fuse BN2.
        if (i == 0)
            gemm_mfma_kernel<64, 256, 256, 256, 1, true, true, true, false>
                <<<NGB, 256, 0, stream>>>(h2, nullptr, nullptr, wpc1,
                                          bt_c1b, aarr + 256, barr + 256, t64c, partY);
        else
            gemm_mfma_kernel<64, 256, 256, 256, 1, true, false, true, false>
                <<<NGB, 256, 0, stream>>>(h2, nullptr, nullptr, wpc1 + (size_t)i * 16384,
                                          bt_c1b + i * 64, nullptr, nullptr, t64c, partY);
        bn_finalize_kernel<<<64, 256, 0, stream>>>(partY, btbn1g + i * 64, btbn1b + i * 64, aA, bA, invN, NGB);

        // cheb2: K=3, 64->64; BN1 fused into gathers and x0-staging
        spmm64_kernel<false, true, false><<<NSP64, 256, 0, stream>>>(t64a, t64c, nullptr, eval_, col, aA, bA);
        spmm64_kernel<true, false, true ><<<NSP64, 256, 0, stream>>>(t64b, t64a, t64c, eval_, col, aA, bA);
        gemm_mfma_kernel<64, 192, 192, 64, 3, true, true, true, false>
            <<<NGB, 256, 0, stream>>>(t64c, t64a, t64b, wpc2 + (size_t)i * 12288,
                                      bt_c2b + i * 64, aA, bA, t64d, partY);
        bn_finalize_kernel<<<64, 256, 0, stream>>>(partY, btbn2g + i * 64, btbn2b + i * 64, aB, bB, invN, NGB);

        // cheb3: K=1, 64->256; BN2 fused into x0-staging; stats partial -> t64c
        gemm_mfma_kernel<256, 64, 64, 64, 1, true, true, true, false>
            <<<NGB, 256, 0, stream>>>(t64d, nullptr, nullptr, wpc3 + (size_t)i * 16384,
                                      bt_c3b + i * 256, aB, bB, y3, partC);
        bn_finalize_kernel<<<256, 256, 0, stream>>>(partC, btbn3g + i * 256, btbn3b + i * 256, aC, bC, invN, NGB);

        // residual: h2 = BN3(y3) + base; base is raw conv2 out for i==0 (apply BN2+relu)
        if (i == 0)
            bn_apply_kernel<256, false, true, true><<<NAPP, 256, 0, stream>>>(
                h2, y3, h2, aC, bC, aarr + 256, barr + 256);
        else
            bn_apply_kernel<256, false, true, false><<<NAPP, 256, 0, stream>>>(
                h2, y3, h2, aC, bC, nullptr, nullptr);
    }

    // ---------- Stage D: conv3 (256 -> 8), commuted: out = z0 - z2 + L(z1 + 2*L*z2) ----------
    float* z0 = t64a;
    float* z1 = z0 + (size_t)BV * 8;
    float* z2 = z1 + (size_t)BV * 8;
    float* ee = z2 + (size_t)BV * 8;

    gemm_mfma_kernel<32, 256, 256, 256, 1, false, false, true, true>
        <<<NGB, 256, 0, stream>>>(h2, nullptr, nullptr, wp3, bpack, nullptr, nullptr, z0, nullptr);

    spmm8_kernel<2><<<BV * 8 / 256, 256, 0, stream>>>(ee, z2, z1, nullptr, eval_, col);
    spmm8_kernel<3><<<BV * 8 / 256, 256, 0, stream>>>(out, ee, z0, z2, eval_, col);

    (void)in_sizes; (void)n_in; (void)out_size; (void)ws_size;
}

// Round 14
// 379.509 us; speedup vs baseline: 1.4481x; 1.1843x over previous
//
#include <hip/hip_runtime.h>

static constexpr int NBRS = 21;
static constexpr int Nv   = 12288;
static constexpr int BV   = 4 * Nv;            // 49152 rows
static constexpr float BN_EPS = 1e-5f;

typedef __bf16 bf16x4 __attribute__((ext_vector_type(4)));
typedef __bf16 bf16x8 __attribute__((ext_vector_type(8)));
typedef float  f32x4  __attribute__((ext_vector_type(4)));

// ---------------- SPMM (C=8, fp32). MODE: 0: y=acc; 1: y=2acc-x0;
// 2: y=2acc+x0; 3: y=acc+x0-x1
template<int MODE>
__global__ void spmm8_kernel(float* __restrict__ y, const float* __restrict__ x,
                             const float* __restrict__ x0, const float* __restrict__ x1,
                             const float* __restrict__ val, const int* __restrict__ col)
{
    int idx = blockIdx.x * 256 + threadIdx.x;
    int c = idx % 8;
    int v = (idx / 8) % Nv;
    int b = idx / (8 * Nv);
    int e0 = v * NBRS;
    float acc = 0.f;
    #pragma unroll
    for (int j = 0; j < NBRS; ++j) {
        int u = col[e0 + j];
        acc = fmaf(val[e0 + j], x[((size_t)b * Nv + u) * 8 + c], acc);
    }
    if (MODE == 0)      y[idx] = acc;
    else if (MODE == 1) y[idx] = 2.f * acc - x0[idx];
    else if (MODE == 2) y[idx] = fmaf(2.f, acc, x0[idx]);
    else                y[idx] = acc + x0[idx] - x1[idx];
}

// ---------------- SPMM C=64, bf16 in/out, fp32 accumulate.
// Optional fused BN+relu on gathered x and/or on x0 (cheb2 variant).
template<bool CHEB2, bool BNG, bool BNX0>
__global__ __launch_bounds__(256)
void spmm64_kernel(__bf16* __restrict__ y, const __bf16* __restrict__ x,
                   const __bf16* __restrict__ x0,
                   const float* __restrict__ val, const int* __restrict__ col,
                   const float* __restrict__ bn_a, const float* __restrict__ bn_b)
{
    int idx = blockIdx.x * 256 + threadIdx.x;   // over BV*16
    int q = idx % 16;
    int v = (idx / 16) % Nv;
    int b = idx / (16 * Nv);
    int e0 = v * NBRS;
    const bf16x4* x4 = (const bf16x4*)x;
    float4 a4, b4;
    if (BNG || (CHEB2 && BNX0)) {
        a4 = ((const float4*)bn_a)[q];
        b4 = ((const float4*)bn_b)[q];
    }
    float4 acc = {0.f, 0.f, 0.f, 0.f};
    #pragma unroll
    for (int j = 0; j < NBRS; ++j) {
        int u = col[e0 + j];
        float a = val[e0 + j];
        bf16x4 hv = x4[(size_t)(b * Nv + u) * 16 + q];
        float x0v = (float)hv[0], x1v = (float)hv[1], x2v = (float)hv[2], x3v = (float)hv[3];
        if (BNG) {
            x0v = fmaxf(fmaf(x0v, a4.x, b4.x), 0.f);
            x1v = fmaxf(fmaf(x1v, a4.y, b4.y), 0.f);
            x2v = fmaxf(fmaf(x2v, a4.z, b4.z), 0.f);
            x3v = fmaxf(fmaf(x3v, a4.w, b4.w), 0.f);
        }
        acc.x = fmaf(a, x0v, acc.x);
        acc.y = fmaf(a, x1v, acc.y);
        acc.z = fmaf(a, x2v, acc.z);
        acc.w = fmaf(a, x3v, acc.w);
    }
    if (CHEB2) {
        bf16x4 pv4 = ((const bf16x4*)x0)[idx];
        float p0 = (float)pv4[0], p1 = (float)pv4[1], p2 = (float)pv4[2], p3 = (float)pv4[3];
        if (BNX0) {
            p0 = fmaxf(fmaf(p0, a4.x, b4.x), 0.f);
            p1 = fmaxf(fmaf(p1, a4.y, b4.y), 0.f);
            p2 = fmaxf(fmaf(p2, a4.z, b4.z), 0.f);
            p3 = fmaxf(fmaf(p3, a4.w, b4.w), 0.f);
        }
        acc.x = 2.f * acc.x - p0;
        acc.y = 2.f * acc.y - p1;
        acc.z = 2.f * acc.z - p2;
        acc.w = 2.f * acc.w - p3;
    }
    bf16x4 o;
    o[0] = (__bf16)acc.x; o[1] = (__bf16)acc.y; o[2] = (__bf16)acc.z; o[3] = (__bf16)acc.w;
    ((bf16x4*)y)[idx] = o;
}

// ---------------- conv3 fp32 pre-pack: [3][256][8] -> [256][32] (+ padded bias)
__global__ void pack_conv3_kernel(const float* __restrict__ w, const float* __restrict__ bias,
                                  float* __restrict__ wpack, float* __restrict__ bpack)
{
    int t = blockIdx.x * 256 + threadIdx.x;
    if (t < 256 * 32) {
        int ki = t / 32, c = t % 32;
        int j = c / 8, o = c % 8;
        wpack[t] = (j < 3) ? w[(size_t)j * 2048 + ki * 8 + o] : 0.f;
    }
    if (t < 32) bpack[t] = (t < 8) ? bias[t] : 0.f;
}

// ---------------- mega-pack: all fp32 weights -> fragment-ordered bf16 arena
__global__ __launch_bounds__(256)
void pack_all_kernel(const float* __restrict__ w1, const float* __restrict__ w2,
                     const float* __restrict__ c1, const float* __restrict__ c2,
                     const float* __restrict__ c3, const float* __restrict__ wpk,
                     __bf16* __restrict__ wb)
{
    int t = blockIdx.x * 256 + threadIdx.x;
    if (t >= 194560) return;
    const float* src; int KSRC, FOUT, local;
    if (t < 2048)        { src = w1;  KSRC = 24;  FOUT = 64;  local = t; }
    else if (t < 51200)  { src = w2;  KSRC = 192; FOUT = 256; local = t - 2048; }
    else if (t < 100352) { int i = (t - 51200) / 16384;  src = c1 + (size_t)i * 16384;
                           KSRC = 256; FOUT = 64;  local = (t - 51200) % 16384; }
    else if (t < 137216) { int i = (t - 100352) / 12288; src = c2 + (size_t)i * 12288;
                           KSRC = 192; FOUT = 64;  local = (t - 100352) % 12288; }
    else if (t < 186368) { int i = (t - 137216) / 16384; src = c3 + (size_t)i * 16384;
                           KSRC = 64;  FOUT = 256; local = (t - 137216) % 16384; }
    else                 { src = wpk; KSRC = 256; FOUT = 32;  local = t - 186368; }
    const int j    = local & 7;
    const int lane = (local >> 3) & 63;
    const int rest = local >> 9;
    const int NT = FOUT >> 4;
    const int nt = rest % NT;
    const int ks = rest / NT;
    const int k = ks * 32 + (lane >> 4) * 8 + j;
    const int o = nt * 16 + (lane & 15);
    wb[t] = (k < KSRC) ? (__bf16)src[(size_t)k * FOUT + o] : (__bf16)0.f;
}

// ---------------- MFMA GEMM. INBF: x sources are bf16; OUTBF: write bf16.
template<int FOUT, int KFIN, int KPAD, int FIN, int NSRC,
         bool STATS, bool BN0, bool HAS_BIAS, bool PACKOUT, bool INBF, bool OUTBF>
__global__ __launch_bounds__(256)
void gemm_mfma_kernel(const void* __restrict__ x0, const void* __restrict__ x1,
                      const void* __restrict__ x2,
                      const __bf16* __restrict__ wp, const float* __restrict__ bias,
                      const float* __restrict__ bn_a, const float* __restrict__ bn_b,
                      void* __restrict__ out, float2* __restrict__ partial)
{
    constexpr int NT    = FOUT / 16;
    constexpr int NSTEP = KPAD / 32;
    constexpr bool COLS = (NT % 4 == 0);
    constexpr int NT2   = COLS ? NT / 4 : NT;
    constexpr int LDKB  = KPAD + 8;
    constexpr int LDC   = FOUT + 4;
    constexpr size_t XS_B  = (size_t)64 * LDKB * 2;
    constexpr size_t RPK_B = COLS ? (size_t)16 * LDC * 4 : 0;
    constexpr size_t SMEM  = XS_B > RPK_B ? XS_B : RPK_B;
    __shared__ __align__(16) char smem[SMEM];
    __bf16* xs = (__bf16*)smem;

    const int tid = threadIdx.x;
    const int m0 = blockIdx.x * 64;

    constexpr int NF4 = 64 * (KPAD / 4);
    for (int f = tid; f < NF4; f += 256) {
        const int r  = f / (KPAD / 4);
        const int ki = (f % (KPAD / 4)) * 4;
        bf16x4 h;
        if (KFIN == KPAD || ki < KFIN) {
            int i; int kk;
            if constexpr (NSRC == 1) { i = ki; kk = 0; }
            else { kk = ki / FIN; i = ki % FIN; }
            if constexpr (INBF) {
                const __bf16* src = (kk == 0) ? (const __bf16*)x0
                                  : (kk == 1 ? (const __bf16*)x1 : (const __bf16*)x2);
                bf16x4 hv = *(const bf16x4*)(src + (size_t)(m0 + r) * FIN + i);
                if (BN0 && (NSRC == 1 || kk == 0)) {
                    const float4 a4 = *(const float4*)(bn_a + i);
                    const float4 b4 = *(const float4*)(bn_b + i);
                    h[0] = (__bf16)fmaxf(fmaf((float)hv[0], a4.x, b4.x), 0.f);
                    h[1] = (__bf16)fmaxf(fmaf((float)hv[1], a4.y, b4.y), 0.f);
                    h[2] = (__bf16)fmaxf(fmaf((float)hv[2], a4.z, b4.z), 0.f);
                    h[3] = (__bf16)fmaxf(fmaf((float)hv[3], a4.w, b4.w), 0.f);
                } else {
                    h = hv;
                }
            } else {
                const float* src = (kk == 0) ? (const float*)x0
                                 : (kk == 1 ? (const float*)x1 : (const float*)x2);
                float4 v = *(const float4*)(src + (size_t)(m0 + r) * FIN + i);
                if (BN0 && (NSRC == 1 || kk == 0)) {
                    const float4 a4 = *(const float4*)(bn_a + i);
                    const float4 b4 = *(const float4*)(bn_b + i);
                    v.x = fmaxf(fmaf(v.x, a4.x, b4.x), 0.f);
                    v.y = fmaxf(fmaf(v.y, a4.y, b4.y), 0.f);
                    v.z = fmaxf(fmaf(v.z, a4.z, b4.z), 0.f);
                    v.w = fmaxf(fmaf(v.w, a4.w, b4.w), 0.f);
                }
                h[0] = (__bf16)v.x; h[1] = (__bf16)v.y; h[2] = (__bf16)v.z; h[3] = (__bf16)v.w;
            }
        } else {
            h[0] = (__bf16)0.f; h[1] = (__bf16)0.f; h[2] = (__bf16)0.f; h[3] = (__bf16)0.f;
        }
        *(bf16x4*)(xs + (size_t)r * LDKB + ki) = h;
    }
    __syncthreads();

    const int lane = tid & 63;
    const int wv   = tid >> 6;
    const int lo   = lane & 15;
    const int hi   = lane >> 4;

    if constexpr (COLS) {
        f32x4 acc[4][NT2];
        #pragma unroll
        for (int mr = 0; mr < 4; ++mr)
            #pragma unroll
            for (int n = 0; n < NT2; ++n) acc[mr][n] = (f32x4){0.f, 0.f, 0.f, 0.f};

        #pragma unroll
        for (int ks = 0; ks < NSTEP; ++ks) {
            bf16x8 bfr[NT2];
            #pragma unroll
            for (int n = 0; n < NT2; ++n)
                bfr[n] = *(const bf16x8*)(wp + ((size_t)(ks * NT + wv * NT2 + n) * 64 + lane) * 8);
            bf16x8 afr[4];
            #pragma unroll
            for (int mr = 0; mr < 4; ++mr)
                afr[mr] = *(const bf16x8*)(xs + (size_t)(mr * 16 + lo) * LDKB + ks * 32 + hi * 8);
            #pragma unroll
            for (int n = 0; n < NT2; ++n)
                #pragma unroll
                for (int mr = 0; mr < 4; ++mr)
                    acc[mr][n] = __builtin_amdgcn_mfma_f32_16x16x32_bf16(afr[mr], bfr[n], acc[mr][n], 0, 0, 0);
        }

        #pragma unroll
        for (int n = 0; n < NT2; ++n) {
            const int o = wv * (FOUT / 4) + n * 16 + lo;
            const float bo = HAS_BIAS ? bias[o] : 0.f;
            #pragma unroll
            for (int mr = 0; mr < 4; ++mr)
                #pragma unroll
                for (int j = 0; j < 4; ++j) acc[mr][n][j] += bo;
        }

        if constexpr (STATS) {
            #pragma unroll
            for (int n = 0; n < NT2; ++n) {
                float s = 0.f, q = 0.f;
                #pragma unroll
                for (int mr = 0; mr < 4; ++mr)
                    #pragma unroll
                    for (int j = 0; j < 4; ++j) {
                        const float v = acc[mr][n][j];
                        s += v; q = fmaf(v, v, q);
                    }
                s += __shfl_xor(s, 16); q += __shfl_xor(q, 16);
                s += __shfl_xor(s, 32); q += __shfl_xor(q, 32);
                if (lane < 16) {
                    const int o = wv * (FOUT / 4) + n * 16 + lo;
                    partial[(size_t)o * gridDim.x + blockIdx.x] = make_float2(s, q);
                }
            }
        }

        float* cs = (float*)smem;
        #pragma unroll
        for (int mr = 0; mr < 4; ++mr) {
            __syncthreads();
            #pragma unroll
            for (int n = 0; n < NT2; ++n) {
                const int o = wv * (FOUT / 4) + n * 16 + lo;
                #pragma unroll
                for (int j = 0; j < 4; ++j)
                    cs[(size_t)(hi * 4 + j) * LDC + o] = acc[mr][n][j];
            }
            __syncthreads();
            for (int t = tid; t < 16 * (FOUT / 4); t += 256) {
                const int rr = t / (FOUT / 4);
                const int c4 = (t % (FOUT / 4)) * 4;
                const float4 v = *(const float4*)(cs + (size_t)rr * LDC + c4);
                if constexpr (OUTBF) {
                    bf16x4 hv;
                    hv[0] = (__bf16)v.x; hv[1] = (__bf16)v.y;
                    hv[2] = (__bf16)v.z; hv[3] = (__bf16)v.w;
                    *(bf16x4*)((__bf16*)out + (size_t)(m0 + mr * 16 + rr) * FOUT + c4) = hv;
                } else {
                    *(float4*)((float*)out + (size_t)(m0 + mr * 16 + rr) * FOUT + c4) = v;
                }
            }
        }
    } else {
        f32x4 acc[NT];
        #pragma unroll
        for (int nt = 0; nt < NT; ++nt) acc[nt] = (f32x4){0.f, 0.f, 0.f, 0.f};
        const int arow = wv * 16 + lo;
        #pragma unroll
        for (int ks = 0; ks < NSTEP; ++ks) {
            const bf16x8 a = *(const bf16x8*)(xs + (size_t)arow * LDKB + ks * 32 + hi * 8);
            #pragma unroll
            for (int nt = 0; nt < NT; ++nt) {
                const bf16x8 b = *(const bf16x8*)(wp + ((size_t)(ks * NT + nt) * 64 + lane) * 8);
                acc[nt] = __builtin_amdgcn_mfma_f32_16x16x32_bf16(a, b, acc[nt], 0, 0, 0);
            }
        }
        #pragma unroll
        for (int nt = 0; nt < NT; ++nt) {
            const int o = nt * 16 + lo;
            const float bo = HAS_BIAS ? bias[o] : 0.f;
            #pragma unroll
            for (int j = 0; j < 4; ++j) {
                const float v = acc[nt][j] + bo;
                const int m = m0 + wv * 16 + hi * 4 + j;
                if constexpr (PACKOUT) {
                    const int zj = o >> 3;
                    if (zj < 3) ((float*)out)[((size_t)zj * BV + m) * 8 + (o & 7)] = v;
                } else {
                    ((float*)out)[(size_t)m * FOUT + o] = v;
                }
            }
        }
    }
}

// ---------------- BN finalize: one block per channel, coalesced over [C][nblk]
__global__ __launch_bounds__(256)
void bn_finalize_kernel(const float2* __restrict__ partial,
                        const float* __restrict__ g, const float* __restrict__ b,
                        float* __restrict__ a_out, float* __restrict__ b_out,
                        float invN, int nblk)
{
    __shared__ float2 red[4];
    const int c = blockIdx.x;
    const float2* p = partial + (size_t)c * nblk;
    float s = 0.f, ss = 0.f;
    for (int k = threadIdx.x; k < nblk; k += 256) {
        const float2 v = p[k];
        s += v.x; ss += v.y;
    }
    #pragma unroll
    for (int off = 32; off > 0; off >>= 1) {
        s  += __shfl_down(s, off);
        ss += __shfl_down(ss, off);
    }
    if ((threadIdx.x & 63) == 0) red[threadIdx.x >> 6] = make_float2(s, ss);
    __syncthreads();
    if (threadIdx.x == 0) {
        float ts = 0.f, tq = 0.f;
        #pragma unroll
        for (int i = 0; i < 4; ++i) { ts += red[i].x; tq += red[i].y; }
        const float m = ts * invN;
        const float var = tq * invN - m * m;
        const float a = g[c] * rsqrtf(var + BN_EPS);
        a_out[c] = a;
        b_out[c] = b[c] - m * a;
    }
}

// ---------------- BN apply: x is bf16 (cheb3 out), base/out fp32.
// BASEBN: base first gets relu(BN2(base)).
template<int C, bool BASEBN>
__global__ __launch_bounds__(256)
void bn_apply_kernel(float* __restrict__ out, const __bf16* __restrict__ x,
                     const float* __restrict__ base,
                     const float* __restrict__ bn_a, const float* __restrict__ bn_b,
                     const float* __restrict__ bn_a2, const float* __restrict__ bn_b2)
{
    int i = blockIdx.x * 256 + threadIdx.x;   // 4-elem index
    bf16x4 hv = ((const bf16x4*)x)[i];
    int c0 = (i * 4) % C;
    float4 a4 = *reinterpret_cast<const float4*>(bn_a + c0);
    float4 b4 = *reinterpret_cast<const float4*>(bn_b + c0);
    float4 r;
    r.x = fmaf((float)hv[0], a4.x, b4.x);
    r.y = fmaf((float)hv[1], a4.y, b4.y);
    r.z = fmaf((float)hv[2], a4.z, b4.z);
    r.w = fmaf((float)hv[3], a4.w, b4.w);
    float4 bvv = ((const float4*)base)[i];
    if (BASEBN) {
        float4 p4 = *reinterpret_cast<const float4*>(bn_a2 + c0);
        float4 q4 = *reinterpret_cast<const float4*>(bn_b2 + c0);
        bvv.x = fmaxf(fmaf(bvv.x, p4.x, q4.x), 0.f);
        bvv.y = fmaxf(fmaf(bvv.y, p4.y, q4.y), 0.f);
        bvv.z = fmaxf(fmaf(bvv.z, p4.z, q4.z), 0.f);
        bvv.w = fmaxf(fmaf(bvv.w, p4.w, q4.w), 0.f);
    }
    r.x += bvv.x; r.y += bvv.y; r.z += bvv.z; r.w += bvv.w;
    ((float4*)out)[i] = r;
}

extern "C" void kernel_launch(void* const* d_in, const int* in_sizes, int n_in,
                              void* d_out, int out_size, void* d_ws, size_t ws_size,
                              hipStream_t stream)
{
    const float* x       = (const float*)d_in[0];
    const int*   col     = (const int*)  d_in[2];
    const float* eval_   = (const float*)d_in[3];
    const float* conv1_w = (const float*)d_in[4];
    const float* conv1_b = (const float*)d_in[5];
    const float* bn1_g   = (const float*)d_in[6];
    const float* bn1_b   = (const float*)d_in[7];
    const float* conv2_w = (const float*)d_in[8];
    const float* conv2_b = (const float*)d_in[9];
    const float* bn2_g   = (const float*)d_in[10];
    const float* bn2_b   = (const float*)d_in[11];
    const float* bt_c1w  = (const float*)d_in[12];
    const float* bt_c1b  = (const float*)d_in[13];
    const float* bt_c2w  = (const float*)d_in[14];
    const float* bt_c2b  = (const float*)d_in[15];
    const float* bt_c3w  = (const float*)d_in[16];
    const float* bt_c3b  = (const float*)d_in[17];
    const float* btbn1g  = (const float*)d_in[18];
    const float* btbn1b  = (const float*)d_in[19];
    const float* btbn2g  = (const float*)d_in[20];
    const float* btbn2b  = (const float*)d_in[21];
    const float* btbn3g  = (const float*)d_in[22];
    const float* btbn3b  = (const float*)d_in[23];
    const float* conv3_w = (const float*)d_in[24];
    const float* conv3_b = (const float*)d_in[25];
    float* out = (float*)d_out;

    float*  h2   = (float*)d_ws;                   // BV*256 fp32 (trunk)
    __bf16* y3b  = (__bf16*)(h2 + (size_t)BV * 256);   // BV*256 bf16 (cheb3 out)
    __bf16* tb   = y3b + (size_t)BV * 256;         // 4 x BV*64 bf16
    __bf16* t64a = tb;
    __bf16* t64b = t64a + (size_t)BV * 64;
    __bf16* t64c = t64b + (size_t)BV * 64;
    __bf16* t64d = t64c + (size_t)BV * 64;
    float*  scr  = (float*)(t64d + (size_t)BV * 64);   // BV*32 fp32 (t8a/t8b, z0..ee)
    float*  aarr = scr + (size_t)BV * 32;          // 11*256
    float*  barr = aarr + 11 * 256;                // 11*256
    float*  wpack = barr + 11 * 256;               // 256*32 fp32
    float*  bpack = wpack + 256 * 32;              // 32
    __bf16* wb   = (__bf16*)(bpack + 32);          // bf16 weight arena
    __bf16* wp1  = wb;                             // 2048
    __bf16* wp2  = wp1 + 2048;                     // 49152
    __bf16* wpc1 = wp2 + 49152;                    // 49152
    __bf16* wpc2 = wpc1 + 49152;                   // 36864
    __bf16* wpc3 = wpc2 + 36864;                   // 49152
    __bf16* wp3  = wpc3 + 49152;                   // 8192
    float2* part = (float2*)(wp3 + 8192);          // 256 * 768

    float* t8a = scr;                              // BV*8 (stage A)
    float* t8b = scr + (size_t)BV * 8;

    const float invN = 1.f / (float)BV;
    const int NGB  = BV / 64;                      // 768
    const int NAPP = BV * 64;                      // 4-elem groups total
    const int NSP64 = BV * 16 / 256;               // 3072

    // ---------- packing ----------
    pack_conv3_kernel<<<32, 256, 0, stream>>>(conv3_w, conv3_b, wpack, bpack);
    pack_all_kernel<<<760, 256, 0, stream>>>(conv1_w, conv2_w, bt_c1w, bt_c2w, bt_c3w, wpack, wb);

    // ---------- Stage A: conv1 (8 -> 64), K=3 (fp32 in, bf16 out) ----------
    spmm8_kernel<0><<<BV * 8 / 256, 256, 0, stream>>>(t8a, x, nullptr, nullptr, eval_, col);
    spmm8_kernel<1><<<BV * 8 / 256, 256, 0, stream>>>(t8b, t8a, x, nullptr, eval_, col);
    gemm_mfma_kernel<64, 24, 32, 8, 3, true, false, true, false, false, true>
        <<<NGB, 256, 0, stream>>>(x, t8a, t8b, wp1, conv1_b, nullptr, nullptr, t64c, part);
    bn_finalize_kernel<<<64, 256, 0, stream>>>(part, bn1_g, bn1_b, aarr, barr, invN, NGB);

    // ---------- Stage B: conv2 (64 -> 256), K=3; h2 RAW fp32 ----------
    spmm64_kernel<false, true, false><<<NSP64, 256, 0, stream>>>(t64a, t64c, nullptr, eval_, col, aarr, barr);
    spmm64_kernel<true, false, true ><<<NSP64, 256, 0, stream>>>(t64b, t64a, t64c, eval_, col, aarr, barr);
    gemm_mfma_kernel<256, 192, 192, 64, 3, true, true, true, false, true, false>
        <<<NGB, 256, 0, stream>>>(t64c, t64a, t64b, wp2, conv2_b, aarr, barr, h2, part);
    bn_finalize_kernel<<<256, 256, 0, stream>>>(part, bn2_g, bn2_b, aarr + 256, barr + 256, invN, NGB);

    // ---------- Stage C: 3 bottlenecks ----------
    for (int i = 0; i < 3; ++i) {
        float* aA = aarr + (2 + i * 3) * 256; float* bA = barr + (2 + i * 3) * 256;
        float* aB = aarr + (3 + i * 3) * 256; float* bB = barr + (3 + i * 3) * 256;
        float* aC = aarr + (4 + i * 3) * 256; float* bC = barr + (4 + i * 3) * 256;

        // cheb1: 256->64, h2 fp32 in (BN2 fused for i=0), t64c bf16 out
        if (i == 0)
            gemm_mfma_kernel<64, 256, 256, 256, 1, true, true, true, false, false, true>
                <<<NGB, 256, 0, stream>>>(h2, nullptr, nullptr, wpc1,
                                          bt_c1b, aarr + 256, barr + 256, t64c, part);
        else
            gemm_mfma_kernel<64, 256, 256, 256, 1, true, false, true, false, false, true>
                <<<NGB, 256, 0, stream>>>(h2, nullptr, nullptr, wpc1 + (size_t)i * 16384,
                                          bt_c1b + i * 64, nullptr, nullptr, t64c, part);
        bn_finalize_kernel<<<64, 256, 0, stream>>>(part, btbn1g + i * 64, btbn1b + i * 64, aA, bA, invN, NGB);

        // cheb2: K=3, 64->64, all bf16; BN1 fused into gathers and x0-staging
        spmm64_kernel<false, true, false><<<NSP64, 256, 0, stream>>>(t64a, t64c, nullptr, eval_, col, aA, bA);
        spmm64_kernel<true, false, true ><<<NSP64, 256, 0, stream>>>(t64b, t64a, t64c, eval_, col, aA, bA);
        gemm_mfma_kernel<64, 192, 192, 64, 3, true, true, true, false, true, true>
            <<<NGB, 256, 0, stream>>>(t64c, t64a, t64b, wpc2 + (size_t)i * 12288,
                                      bt_c2b + i * 64, aA, bA, t64d, part);
        bn_finalize_kernel<<<64, 256, 0, stream>>>(part, btbn2g + i * 64, btbn2b + i * 64, aB, bB, invN, NGB);

        // cheb3: 64->256, t64d bf16 in (BN2 fused), y3b bf16 out
        gemm_mfma_kernel<256, 64, 64, 64, 1, true, true, true, false, true, true>
            <<<NGB, 256, 0, stream>>>(t64d, nullptr, nullptr, wpc3 + (size_t)i * 16384,
                                      bt_c3b + i * 256, aB, bB, y3b, part);
        bn_finalize_kernel<<<256, 256, 0, stream>>>(part, btbn3g + i * 256, btbn3b + i * 256, aC, bC, invN, NGB);

        // residual: h2 = BN3(y3b) + base (base=raw conv2 for i=0: BN2+relu fused)
        if (i == 0)
            bn_apply_kernel<256, true><<<NAPP / 256, 256, 0, stream>>>(
                h2, y3b, h2, aC, bC, aarr + 256, barr + 256);
        else
            bn_apply_kernel<256, false><<<NAPP / 256, 256, 0, stream>>>(
                h2, y3b, h2, aC, bC, nullptr, nullptr);
    }

    // ---------- Stage D: conv3 (256 -> 8), commuted: out = z0 - z2 + L(z1 + 2*L*z2) ----------
    float* z0 = scr;
    float* z1 = z0 + (size_t)BV * 8;
    float* z2 = z1 + (size_t)BV * 8;
    float* ee = z2 + (size_t)BV * 8;

    gemm_mfma_kernel<32, 256, 256, 256, 1, false, false, true, true, false, false>
        <<<NGB, 256, 0, stream>>>(h2, nullptr, nullptr, wp3, bpack, nullptr, nullptr, z0, nullptr);

    spmm8_kernel<2><<<BV * 8 / 256, 256, 0, stream>>>(ee, z2, z1, nullptr, eval_, col);
    spmm8_kernel<3><<<BV * 8 / 256, 256, 0, stream>>>(out, ee, z0, z2, eval_, col);

    (void)in_sizes; (void)n_in; (void)out_size; (void)ws_size;
}

// Round 15
// 341.405 us; speedup vs baseline: 1.6097x; 1.1116x over previous
//
#include <hip/hip_runtime.h>

static constexpr int NBRS = 21;
static constexpr int Nv   = 12288;
static constexpr int BV   = 4 * Nv;            // 49152 rows
static constexpr float BN_EPS = 1e-5f;

typedef __bf16 bf16x4 __attribute__((ext_vector_type(4)));
typedef __bf16 bf16x8 __attribute__((ext_vector_type(8)));
typedef float  f32x4  __attribute__((ext_vector_type(4)));

// ---------------- SPMM (C=8, fp32). MODE: 0: y=acc; 1: y=2acc-x0;
// 2: y=2acc+x0; 3: y=acc+x0-x1
template<int MODE>
__global__ void spmm8_kernel(float* __restrict__ y, const float* __restrict__ x,
                             const float* __restrict__ x0, const float* __restrict__ x1,
                             const float* __restrict__ val, const int* __restrict__ col)
{
    int idx = blockIdx.x * 256 + threadIdx.x;
    int c = idx % 8;
    int v = (idx / 8) % Nv;
    int b = idx / (8 * Nv);
    int e0 = v * NBRS;
    float acc = 0.f;
    #pragma unroll
    for (int j = 0; j < NBRS; ++j) {
        int u = col[e0 + j];
        acc = fmaf(val[e0 + j], x[((size_t)b * Nv + u) * 8 + c], acc);
    }
    if (MODE == 0)      y[idx] = acc;
    else if (MODE == 1) y[idx] = 2.f * acc - x0[idx];
    else if (MODE == 2) y[idx] = fmaf(2.f, acc, x0[idx]);
    else                y[idx] = acc + x0[idx] - x1[idx];
}

// ---------------- SPMM C=64, bf16 in/out, fp32 accumulate.
template<bool CHEB2, bool BNG, bool BNX0>
__global__ __launch_bounds__(256)
void spmm64_kernel(__bf16* __restrict__ y, const __bf16* __restrict__ x,
                   const __bf16* __restrict__ x0,
                   const float* __restrict__ val, const int* __restrict__ col,
                   const float* __restrict__ bn_a, const float* __restrict__ bn_b)
{
    int idx = blockIdx.x * 256 + threadIdx.x;   // over BV*16
    int q = idx % 16;
    int v = (idx / 16) % Nv;
    int b = idx / (16 * Nv);
    int e0 = v * NBRS;
    const bf16x4* x4 = (const bf16x4*)x;
    float4 a4, b4;
    if (BNG || (CHEB2 && BNX0)) {
        a4 = ((const float4*)bn_a)[q];
        b4 = ((const float4*)bn_b)[q];
    }
    float4 acc = {0.f, 0.f, 0.f, 0.f};
    #pragma unroll
    for (int j = 0; j < NBRS; ++j) {
        int u = col[e0 + j];
        float a = val[e0 + j];
        bf16x4 hv = x4[(size_t)(b * Nv + u) * 16 + q];
        float x0v = (float)hv[0], x1v = (float)hv[1], x2v = (float)hv[2], x3v = (float)hv[3];
        if (BNG) {
            x0v = fmaxf(fmaf(x0v, a4.x, b4.x), 0.f);
            x1v = fmaxf(fmaf(x1v, a4.y, b4.y), 0.f);
            x2v = fmaxf(fmaf(x2v, a4.z, b4.z), 0.f);
            x3v = fmaxf(fmaf(x3v, a4.w, b4.w), 0.f);
        }
        acc.x = fmaf(a, x0v, acc.x);
        acc.y = fmaf(a, x1v, acc.y);
        acc.z = fmaf(a, x2v, acc.z);
        acc.w = fmaf(a, x3v, acc.w);
    }
    if (CHEB2) {
        bf16x4 pv4 = ((const bf16x4*)x0)[idx];
        float p0 = (float)pv4[0], p1 = (float)pv4[1], p2 = (float)pv4[2], p3 = (float)pv4[3];
        if (BNX0) {
            p0 = fmaxf(fmaf(p0, a4.x, b4.x), 0.f);
            p1 = fmaxf(fmaf(p1, a4.y, b4.y), 0.f);
            p2 = fmaxf(fmaf(p2, a4.z, b4.z), 0.f);
            p3 = fmaxf(fmaf(p3, a4.w, b4.w), 0.f);
        }
        acc.x = 2.f * acc.x - p0;
        acc.y = 2.f * acc.y - p1;
        acc.z = 2.f * acc.z - p2;
        acc.w = 2.f * acc.w - p3;
    }
    bf16x4 o;
    o[0] = (__bf16)acc.x; o[1] = (__bf16)acc.y; o[2] = (__bf16)acc.z; o[3] = (__bf16)acc.w;
    ((bf16x4*)y)[idx] = o;
}

// ---------------- conv3 fp32 pre-pack: [3][256][8] -> [256][32] (+ padded bias)
__global__ void pack_conv3_kernel(const float* __restrict__ w, const float* __restrict__ bias,
                                  float* __restrict__ wpack, float* __restrict__ bpack)
{
    int t = blockIdx.x * 256 + threadIdx.x;
    if (t < 256 * 32) {
        int ki = t / 32, c = t % 32;
        int j = c / 8, o = c % 8;
        wpack[t] = (j < 3) ? w[(size_t)j * 2048 + ki * 8 + o] : 0.f;
    }
    if (t < 32) bpack[t] = (t < 8) ? bias[t] : 0.f;
}

// ---------------- mega-pack: all fp32 weights -> fragment-ordered bf16 arena
__global__ __launch_bounds__(256)
void pack_all_kernel(const float* __restrict__ w1, const float* __restrict__ w2,
                     const float* __restrict__ c1, const float* __restrict__ c2,
                     const float* __restrict__ c3, const float* __restrict__ wpk,
                     __bf16* __restrict__ wb)
{
    int t = blockIdx.x * 256 + threadIdx.x;
    if (t >= 194560) return;
    const float* src; int KSRC, FOUT, local;
    if (t < 2048)        { src = w1;  KSRC = 24;  FOUT = 64;  local = t; }
    else if (t < 51200)  { src = w2;  KSRC = 192; FOUT = 256; local = t - 2048; }
    else if (t < 100352) { int i = (t - 51200) / 16384;  src = c1 + (size_t)i * 16384;
                           KSRC = 256; FOUT = 64;  local = (t - 51200) % 16384; }
    else if (t < 137216) { int i = (t - 100352) / 12288; src = c2 + (size_t)i * 12288;
                           KSRC = 192; FOUT = 64;  local = (t - 100352) % 12288; }
    else if (t < 186368) { int i = (t - 137216) / 16384; src = c3 + (size_t)i * 16384;
                           KSRC = 64;  FOUT = 256; local = (t - 137216) % 16384; }
    else                 { src = wpk; KSRC = 256; FOUT = 32;  local = t - 186368; }
    const int j    = local & 7;
    const int lane = (local >> 3) & 63;
    const int rest = local >> 9;
    const int NT = FOUT >> 4;
    const int nt = rest % NT;
    const int ks = rest / NT;
    const int k = ks * 32 + (lane >> 4) * 8 + j;
    const int o = nt * 16 + (lane & 15);
    wb[t] = (k < KSRC) ? (__bf16)src[(size_t)k * FOUT + o] : (__bf16)0.f;
}

// ---------------- MFMA GEMM. INBF: x bf16; OUTBF: write bf16.
// RESID (NSRC=1, INBF): stage = BN(x0) + x1 (both bf16; fused residual).
template<int FOUT, int KFIN, int KPAD, int FIN, int NSRC,
         bool STATS, bool BN0, bool HAS_BIAS, bool PACKOUT, bool INBF, bool OUTBF,
         bool RESID = false>
__global__ __launch_bounds__(256)
void gemm_mfma_kernel(const void* __restrict__ x0, const void* __restrict__ x1,
                      const void* __restrict__ x2,
                      const __bf16* __restrict__ wp, const float* __restrict__ bias,
                      const float* __restrict__ bn_a, const float* __restrict__ bn_b,
                      void* __restrict__ out, float2* __restrict__ partial)
{
    constexpr int NT    = FOUT / 16;
    constexpr int NSTEP = KPAD / 32;
    constexpr bool COLS = (NT % 4 == 0);
    constexpr int NT2   = COLS ? NT / 4 : NT;
    constexpr int LDKB  = KPAD + 8;
    constexpr int LDC   = FOUT + 4;
    constexpr size_t XS_B  = (size_t)64 * LDKB * 2;
    constexpr size_t RPK_B = COLS ? (size_t)16 * LDC * 4 : 0;
    constexpr size_t SMEM  = XS_B > RPK_B ? XS_B : RPK_B;
    __shared__ __align__(16) char smem[SMEM];
    __bf16* xs = (__bf16*)smem;

    const int tid = threadIdx.x;
    const int m0 = blockIdx.x * 64;

    constexpr int NF4 = 64 * (KPAD / 4);
    for (int f = tid; f < NF4; f += 256) {
        const int r  = f / (KPAD / 4);
        const int ki = (f % (KPAD / 4)) * 4;
        bf16x4 h;
        if (KFIN == KPAD || ki < KFIN) {
            int i; int kk;
            if constexpr (NSRC == 1) { i = ki; kk = 0; }
            else { kk = ki / FIN; i = ki % FIN; }
            if constexpr (RESID) {
                const __bf16* srcy = (const __bf16*)x0;
                const __bf16* srct = (const __bf16*)x1;
                bf16x4 hy = *(const bf16x4*)(srcy + (size_t)(m0 + r) * FIN + i);
                bf16x4 ht = *(const bf16x4*)(srct + (size_t)(m0 + r) * FIN + i);
                const float4 a4 = *(const float4*)(bn_a + i);
                const float4 b4 = *(const float4*)(bn_b + i);
                h[0] = (__bf16)(fmaf((float)hy[0], a4.x, b4.x) + (float)ht[0]);
                h[1] = (__bf16)(fmaf((float)hy[1], a4.y, b4.y) + (float)ht[1]);
                h[2] = (__bf16)(fmaf((float)hy[2], a4.z, b4.z) + (float)ht[2]);
                h[3] = (__bf16)(fmaf((float)hy[3], a4.w, b4.w) + (float)ht[3]);
            } else if constexpr (INBF) {
                const __bf16* src = (kk == 0) ? (const __bf16*)x0
                                  : (kk == 1 ? (const __bf16*)x1 : (const __bf16*)x2);
                bf16x4 hv = *(const bf16x4*)(src + (size_t)(m0 + r) * FIN + i);
                if (BN0 && (NSRC == 1 || kk == 0)) {
                    const float4 a4 = *(const float4*)(bn_a + i);
                    const float4 b4 = *(const float4*)(bn_b + i);
                    h[0] = (__bf16)fmaxf(fmaf((float)hv[0], a4.x, b4.x), 0.f);
                    h[1] = (__bf16)fmaxf(fmaf((float)hv[1], a4.y, b4.y), 0.f);
                    h[2] = (__bf16)fmaxf(fmaf((float)hv[2], a4.z, b4.z), 0.f);
                    h[3] = (__bf16)fmaxf(fmaf((float)hv[3], a4.w, b4.w), 0.f);
                } else {
                    h = hv;
                }
            } else {
                const float* src = (kk == 0) ? (const float*)x0
                                 : (kk == 1 ? (const float*)x1 : (const float*)x2);
                float4 v = *(const float4*)(src + (size_t)(m0 + r) * FIN + i);
                if (BN0 && (NSRC == 1 || kk == 0)) {
                    const float4 a4 = *(const float4*)(bn_a + i);
                    const float4 b4 = *(const float4*)(bn_b + i);
                    v.x = fmaxf(fmaf(v.x, a4.x, b4.x), 0.f);
                    v.y = fmaxf(fmaf(v.y, a4.y, b4.y), 0.f);
                    v.z = fmaxf(fmaf(v.z, a4.z, b4.z), 0.f);
                    v.w = fmaxf(fmaf(v.w, a4.w, b4.w), 0.f);
                }
                h[0] = (__bf16)v.x; h[1] = (__bf16)v.y; h[2] = (__bf16)v.z; h[3] = (__bf16)v.w;
            }
        } else {
            h[0] = (__bf16)0.f; h[1] = (__bf16)0.f; h[2] = (__bf16)0.f; h[3] = (__bf16)0.f;
        }
        *(bf16x4*)(xs + (size_t)r * LDKB + ki) = h;
    }
    __syncthreads();

    const int lane = tid & 63;
    const int wv   = tid >> 6;
    const int lo   = lane & 15;
    const int hi   = lane >> 4;

    if constexpr (COLS) {
        f32x4 acc[4][NT2];
        #pragma unroll
        for (int mr = 0; mr < 4; ++mr)
            #pragma unroll
            for (int n = 0; n < NT2; ++n) acc[mr][n] = (f32x4){0.f, 0.f, 0.f, 0.f};

        #pragma unroll
        for (int ks = 0; ks < NSTEP; ++ks) {
            bf16x8 bfr[NT2];
            #pragma unroll
            for (int n = 0; n < NT2; ++n)
                bfr[n] = *(const bf16x8*)(wp + ((size_t)(ks * NT + wv * NT2 + n) * 64 + lane) * 8);
            bf16x8 afr[4];
            #pragma unroll
            for (int mr = 0; mr < 4; ++mr)
                afr[mr] = *(const bf16x8*)(xs + (size_t)(mr * 16 + lo) * LDKB + ks * 32 + hi * 8);
            #pragma unroll
            for (int n = 0; n < NT2; ++n)
                #pragma unroll
                for (int mr = 0; mr < 4; ++mr)
                    acc[mr][n] = __builtin_amdgcn_mfma_f32_16x16x32_bf16(afr[mr], bfr[n], acc[mr][n], 0, 0, 0);
        }

        #pragma unroll
        for (int n = 0; n < NT2; ++n) {
            const int o = wv * (FOUT / 4) + n * 16 + lo;
            const float bo = HAS_BIAS ? bias[o] : 0.f;
            #pragma unroll
            for (int mr = 0; mr < 4; ++mr)
                #pragma unroll
                for (int j = 0; j < 4; ++j) acc[mr][n][j] += bo;
        }

        if constexpr (STATS) {
            #pragma unroll
            for (int n = 0; n < NT2; ++n) {
                float s = 0.f, q = 0.f;
                #pragma unroll
                for (int mr = 0; mr < 4; ++mr)
                    #pragma unroll
                    for (int j = 0; j < 4; ++j) {
                        const float v = acc[mr][n][j];
                        s += v; q = fmaf(v, v, q);
                    }
                s += __shfl_xor(s, 16); q += __shfl_xor(q, 16);
                s += __shfl_xor(s, 32); q += __shfl_xor(q, 32);
                if (lane < 16) {
                    const int o = wv * (FOUT / 4) + n * 16 + lo;
                    partial[(size_t)o * gridDim.x + blockIdx.x] = make_float2(s, q);
                }
            }
        }

        float* cs = (float*)smem;
        #pragma unroll
        for (int mr = 0; mr < 4; ++mr) {
            __syncthreads();
            #pragma unroll
            for (int n = 0; n < NT2; ++n) {
                const int o = wv * (FOUT / 4) + n * 16 + lo;
                #pragma unroll
                for (int j = 0; j < 4; ++j)
                    cs[(size_t)(hi * 4 + j) * LDC + o] = acc[mr][n][j];
            }
            __syncthreads();
            for (int t = tid; t < 16 * (FOUT / 4); t += 256) {
                const int rr = t / (FOUT / 4);
                const int c4 = (t % (FOUT / 4)) * 4;
                const float4 v = *(const float4*)(cs + (size_t)rr * LDC + c4);
                if constexpr (OUTBF) {
                    bf16x4 hv;
                    hv[0] = (__bf16)v.x; hv[1] = (__bf16)v.y;
                    hv[2] = (__bf16)v.z; hv[3] = (__bf16)v.w;
                    *(bf16x4*)((__bf16*)out + (size_t)(m0 + mr * 16 + rr) * FOUT + c4) = hv;
                } else {
                    *(float4*)((float*)out + (size_t)(m0 + mr * 16 + rr) * FOUT + c4) = v;
                }
            }
        }
    } else {
        f32x4 acc[NT];
        #pragma unroll
        for (int nt = 0; nt < NT; ++nt) acc[nt] = (f32x4){0.f, 0.f, 0.f, 0.f};
        const int arow = wv * 16 + lo;
        #pragma unroll
        for (int ks = 0; ks < NSTEP; ++ks) {
            const bf16x8 a = *(const bf16x8*)(xs + (size_t)arow * LDKB + ks * 32 + hi * 8);
            #pragma unroll
            for (int nt = 0; nt < NT; ++nt) {
                const bf16x8 b = *(const bf16x8*)(wp + ((size_t)(ks * NT + nt) * 64 + lane) * 8);
                acc[nt] = __builtin_amdgcn_mfma_f32_16x16x32_bf16(a, b, acc[nt], 0, 0, 0);
            }
        }
        #pragma unroll
        for (int nt = 0; nt < NT; ++nt) {
            const int o = nt * 16 + lo;
            const float bo = HAS_BIAS ? bias[o] : 0.f;
            #pragma unroll
            for (int j = 0; j < 4; ++j) {
                const float v = acc[nt][j] + bo;
                const int m = m0 + wv * 16 + hi * 4 + j;
                if constexpr (PACKOUT) {
                    const int zj = o >> 3;
                    if (zj < 3) ((float*)out)[((size_t)zj * BV + m) * 8 + (o & 7)] = v;
                } else {
                    ((float*)out)[(size_t)m * FOUT + o] = v;
                }
            }
        }
    }
}

// ---------------- BN finalize: one block per channel, coalesced over [C][nblk]
__global__ __launch_bounds__(256)
void bn_finalize_kernel(const float2* __restrict__ partial,
                        const float* __restrict__ g, const float* __restrict__ b,
                        float* __restrict__ a_out, float* __restrict__ b_out,
                        float invN, int nblk)
{
    __shared__ float2 red[4];
    const int c = blockIdx.x;
    const float2* p = partial + (size_t)c * nblk;
    float s = 0.f, ss = 0.f;
    for (int k = threadIdx.x; k < nblk; k += 256) {
        const float2 v = p[k];
        s += v.x; ss += v.y;
    }
    #pragma unroll
    for (int off = 32; off > 0; off >>= 1) {
        s  += __shfl_down(s, off);
        ss += __shfl_down(ss, off);
    }
    if ((threadIdx.x & 63) == 0) red[threadIdx.x >> 6] = make_float2(s, ss);
    __syncthreads();
    if (threadIdx.x == 0) {
        float ts = 0.f, tq = 0.f;
        #pragma unroll
        for (int i = 0; i < 4; ++i) { ts += red[i].x; tq += red[i].y; }
        const float m = ts * invN;
        const float var = tq * invN - m * m;
        const float a = g[c] * rsqrtf(var + BN_EPS);
        a_out[c] = a;
        b_out[c] = b[c] - m * a;
    }
}

// ---------------- BN apply: all-bf16 trunk update. out = BN3(x) + baseproc.
// BASEBN: base first gets relu(BN2(base)).
template<int C, bool BASEBN>
__global__ __launch_bounds__(256)
void bn_apply_kernel(__bf16* __restrict__ out, const __bf16* __restrict__ x,
                     const __bf16* __restrict__ base,
                     const float* __restrict__ bn_a, const float* __restrict__ bn_b,
                     const float* __restrict__ bn_a2, const float* __restrict__ bn_b2)
{
    int i = blockIdx.x * 256 + threadIdx.x;   // 4-elem index
    bf16x4 hv = ((const bf16x4*)x)[i];
    int c0 = (i * 4) % C;
    float4 a4 = *reinterpret_cast<const float4*>(bn_a + c0);
    float4 b4 = *reinterpret_cast<const float4*>(bn_b + c0);
    float r0 = fmaf((float)hv[0], a4.x, b4.x);
    float r1 = fmaf((float)hv[1], a4.y, b4.y);
    float r2 = fmaf((float)hv[2], a4.z, b4.z);
    float r3 = fmaf((float)hv[3], a4.w, b4.w);
    bf16x4 bb = ((const bf16x4*)base)[i];
    float v0 = (float)bb[0], v1 = (float)bb[1], v2 = (float)bb[2], v3 = (float)bb[3];
    if (BASEBN) {
        float4 p4 = *reinterpret_cast<const float4*>(bn_a2 + c0);
        float4 q4 = *reinterpret_cast<const float4*>(bn_b2 + c0);
        v0 = fmaxf(fmaf(v0, p4.x, q4.x), 0.f);
        v1 = fmaxf(fmaf(v1, p4.y, q4.y), 0.f);
        v2 = fmaxf(fmaf(v2, p4.z, q4.z), 0.f);
        v3 = fmaxf(fmaf(v3, p4.w, q4.w), 0.f);
    }
    bf16x4 o;
    o[0] = (__bf16)(r0 + v0);
    o[1] = (__bf16)(r1 + v1);
    o[2] = (__bf16)(r2 + v2);
    o[3] = (__bf16)(r3 + v3);
    ((bf16x4*)out)[i] = o;
}

extern "C" void kernel_launch(void* const* d_in, const int* in_sizes, int n_in,
                              void* d_out, int out_size, void* d_ws, size_t ws_size,
                              hipStream_t stream)
{
    const float* x       = (const float*)d_in[0];
    const int*   col     = (const int*)  d_in[2];
    const float* eval_   = (const float*)d_in[3];
    const float* conv1_w = (const float*)d_in[4];
    const float* conv1_b = (const float*)d_in[5];
    const float* bn1_g   = (const float*)d_in[6];
    const float* bn1_b   = (const float*)d_in[7];
    const float* conv2_w = (const float*)d_in[8];
    const float* conv2_b = (const float*)d_in[9];
    const float* bn2_g   = (const float*)d_in[10];
    const float* bn2_b   = (const float*)d_in[11];
    const float* bt_c1w  = (const float*)d_in[12];
    const float* bt_c1b  = (const float*)d_in[13];
    const float* bt_c2w  = (const float*)d_in[14];
    const float* bt_c2b  = (const float*)d_in[15];
    const float* bt_c3w  = (const float*)d_in[16];
    const float* bt_c3b  = (const float*)d_in[17];
    const float* btbn1g  = (const float*)d_in[18];
    const float* btbn1b  = (const float*)d_in[19];
    const float* btbn2g  = (const float*)d_in[20];
    const float* btbn2b  = (const float*)d_in[21];
    const float* btbn3g  = (const float*)d_in[22];
    const float* btbn3b  = (const float*)d_in[23];
    const float* conv3_w = (const float*)d_in[24];
    const float* conv3_b = (const float*)d_in[25];
    float* out = (float*)d_out;

    __bf16* h2b  = (__bf16*)d_ws;                  // BV*256 bf16 (trunk)
    __bf16* y3b  = h2b + (size_t)BV * 256;         // BV*256 bf16 (cheb3 out)
    __bf16* t64a = y3b + (size_t)BV * 256;         // 4 x BV*64 bf16
    __bf16* t64b = t64a + (size_t)BV * 64;
    __bf16* t64c = t64b + (size_t)BV * 64;
    __bf16* t64d = t64c + (size_t)BV * 64;
    float*  scr  = (float*)(t64d + (size_t)BV * 64);   // BV*32 fp32
    float*  aarr = scr + (size_t)BV * 32;          // 11*256
    float*  barr = aarr + 11 * 256;                // 11*256
    float*  wpack = barr + 11 * 256;               // 256*32 fp32
    float*  bpack = wpack + 256 * 32;              // 32
    __bf16* wb   = (__bf16*)(bpack + 32);          // bf16 weight arena
    __bf16* wp1  = wb;                             // 2048
    __bf16* wp2  = wp1 + 2048;                     // 49152
    __bf16* wpc1 = wp2 + 49152;                    // 49152
    __bf16* wpc2 = wpc1 + 49152;                   // 36864
    __bf16* wpc3 = wpc2 + 36864;                   // 49152
    __bf16* wp3  = wpc3 + 49152;                   // 8192
    float2* part = (float2*)(wp3 + 8192);          // 256 * 768

    float* t8a = scr;                              // BV*8 (stage A)
    float* t8b = scr + (size_t)BV * 8;

    const float invN = 1.f / (float)BV;
    const int NGB  = BV / 64;                      // 768
    const int NSP64 = BV * 16 / 256;               // 3072

    // ---------- packing ----------
    pack_conv3_kernel<<<32, 256, 0, stream>>>(conv3_w, conv3_b, wpack, bpack);
    pack_all_kernel<<<760, 256, 0, stream>>>(conv1_w, conv2_w, bt_c1w, bt_c2w, bt_c3w, wpack, wb);

    // ---------- Stage A: conv1 (8 -> 64), K=3 (fp32 in, bf16 out) ----------
    spmm8_kernel<0><<<BV * 8 / 256, 256, 0, stream>>>(t8a, x, nullptr, nullptr, eval_, col);
    spmm8_kernel<1><<<BV * 8 / 256, 256, 0, stream>>>(t8b, t8a, x, nullptr, eval_, col);
    gemm_mfma_kernel<64, 24, 32, 8, 3, true, false, true, false, false, true>
        <<<NGB, 256, 0, stream>>>(x, t8a, t8b, wp1, conv1_b, nullptr, nullptr, t64c, part);
    bn_finalize_kernel<<<64, 256, 0, stream>>>(part, bn1_g, bn1_b, aarr, barr, invN, NGB);

    // ---------- Stage B: conv2 (64 -> 256), K=3; h2b RAW bf16 ----------
    spmm64_kernel<false, true, false><<<NSP64, 256, 0, stream>>>(t64a, t64c, nullptr, eval_, col, aarr, barr);
    spmm64_kernel<true, false, true ><<<NSP64, 256, 0, stream>>>(t64b, t64a, t64c, eval_, col, aarr, barr);
    gemm_mfma_kernel<256, 192, 192, 64, 3, true, true, true, false, true, true>
        <<<NGB, 256, 0, stream>>>(t64c, t64a, t64b, wp2, conv2_b, aarr, barr, h2b, part);
    bn_finalize_kernel<<<256, 256, 0, stream>>>(part, bn2_g, bn2_b, aarr + 256, barr + 256, invN, NGB);

    // ---------- Stage C: 3 bottlenecks ----------
    for (int i = 0; i < 3; ++i) {
        float* aA = aarr + (2 + i * 3) * 256; float* bA = barr + (2 + i * 3) * 256;
        float* aB = aarr + (3 + i * 3) * 256; float* bB = barr + (3 + i * 3) * 256;
        float* aC = aarr + (4 + i * 3) * 256; float* bC = barr + (4 + i * 3) * 256;

        // cheb1: 256->64, h2b bf16 in (BN2 fused for i=0), t64c bf16 out
        if (i == 0)
            gemm_mfma_kernel<64, 256, 256, 256, 1, true, true, true, false, true, true>
                <<<NGB, 256, 0, stream>>>(h2b, nullptr, nullptr, wpc1,
                                          bt_c1b, aarr + 256, barr + 256, t64c, part);
        else
            gemm_mfma_kernel<64, 256, 256, 256, 1, true, false, true, false, true, true>
                <<<NGB, 256, 0, stream>>>(h2b, nullptr, nullptr, wpc1 + (size_t)i * 16384,
                                          bt_c1b + i * 64, nullptr, nullptr, t64c, part);
        bn_finalize_kernel<<<64, 256, 0, stream>>>(part, btbn1g + i * 64, btbn1b + i * 64, aA, bA, invN, NGB);

        // cheb2: K=3, 64->64, all bf16; BN1 fused into gathers and x0-staging
        spmm64_kernel<false, true, false><<<NSP64, 256, 0, stream>>>(t64a, t64c, nullptr, eval_, col, aA, bA);
        spmm64_kernel<true, false, true ><<<NSP64, 256, 0, stream>>>(t64b, t64a, t64c, eval_, col, aA, bA);
        gemm_mfma_kernel<64, 192, 192, 64, 3, true, true, true, false, true, true>
            <<<NGB, 256, 0, stream>>>(t64c, t64a, t64b, wpc2 + (size_t)i * 12288,
                                      bt_c2b + i * 64, aA, bA, t64d, part);
        bn_finalize_kernel<<<64, 256, 0, stream>>>(part, btbn2g + i * 64, btbn2b + i * 64, aB, bB, invN, NGB);

        // cheb3: 64->256, t64d bf16 in (BN2 fused), y3b bf16 out
        gemm_mfma_kernel<256, 64, 64, 64, 1, true, true, true, false, true, true>
            <<<NGB, 256, 0, stream>>>(t64d, nullptr, nullptr, wpc3 + (size_t)i * 16384,
                                      bt_c3b + i * 256, aB, bB, y3b, part);
        bn_finalize_kernel<<<256, 256, 0, stream>>>(part, btbn3g + i * 256, btbn3b + i * 256, aC, bC, invN, NGB);

        // residual trunk update (skip i=2: fused into conv3 staging)
        if (i == 0)
            bn_apply_kernel<256, true><<<BV / 4, 256, 0, stream>>>(
                h2b, y3b, h2b, aC, bC, aarr + 256, barr + 256);
        else if (i == 1)
            bn_apply_kernel<256, false><<<BV / 4, 256, 0, stream>>>(
                h2b, y3b, h2b, aC, bC, nullptr, nullptr);
    }

    // ---------- Stage D: conv3 with fused final residual (RESID staging) ----------
    float* z0 = scr;
    float* z1 = z0 + (size_t)BV * 8;
    float* z2 = z1 + (size_t)BV * 8;
    float* ee = z2 + (size_t)BV * 8;
    float* aC2 = aarr + 10 * 256;   // i=2 BN3 params
    float* bC2 = barr + 10 * 256;

    gemm_mfma_kernel<32, 256, 256, 256, 1, false, true, true, true, true, false, true>
        <<<NGB, 256, 0, stream>>>(y3b, h2b, nullptr, wp3, bpack, aC2, bC2, z0, nullptr);

    spmm8_kernel<2><<<BV * 8 / 256, 256, 0, stream>>>(ee, z2, z1, nullptr, eval_, col);
    spmm8_kernel<3><<<BV * 8 / 256, 256, 0, stream>>>(out, ee, z0, z2, eval_, col);

    (void)in_sizes; (void)n_in; (void)out_size; (void)ws_size;
}

// Round 16
// 334.461 us; speedup vs baseline: 1.6431x; 1.0208x over previous
//
#include <hip/hip_runtime.h>

static constexpr int NBRS = 21;
static constexpr int Nv   = 12288;
static constexpr int BV   = 4 * Nv;            // 49152 rows
static constexpr float BN_EPS = 1e-5f;

typedef __bf16 bf16x4 __attribute__((ext_vector_type(4)));
typedef __bf16 bf16x8 __attribute__((ext_vector_type(8)));
typedef float  f32x4  __attribute__((ext_vector_type(4)));

// ---------------- SPMM (C=8, fp32, float4: 2 threads/row). MODE:
// 0: y=acc; 1: y=2acc-x0; 2: y=2acc+x0; 3: y=acc+x0-x1
template<int MODE>
__global__ __launch_bounds__(256)
void spmm8_kernel(float* __restrict__ y, const float* __restrict__ x,
                  const float* __restrict__ x0, const float* __restrict__ x1,
                  const float* __restrict__ val, const int* __restrict__ col)
{
    int idx = blockIdx.x * 256 + threadIdx.x;   // over BV*2
    int c4 = idx & 1;
    int row = idx >> 1;
    int v = row % Nv;
    int b = row / Nv;
    int e0 = v * NBRS;
    const float4* x4 = (const float4*)x;
    float4 acc = {0.f, 0.f, 0.f, 0.f};
    #pragma unroll
    for (int j = 0; j < NBRS; ++j) {
        int u = col[e0 + j];
        float a = val[e0 + j];
        float4 xv = x4[(size_t)(b * Nv + u) * 2 + c4];
        acc.x = fmaf(a, xv.x, acc.x);
        acc.y = fmaf(a, xv.y, acc.y);
        acc.z = fmaf(a, xv.z, acc.z);
        acc.w = fmaf(a, xv.w, acc.w);
    }
    if (MODE == 1) {
        float4 p = ((const float4*)x0)[idx];
        acc.x = 2.f * acc.x - p.x; acc.y = 2.f * acc.y - p.y;
        acc.z = 2.f * acc.z - p.z; acc.w = 2.f * acc.w - p.w;
    } else if (MODE == 2) {
        float4 p = ((const float4*)x0)[idx];
        acc.x = fmaf(2.f, acc.x, p.x); acc.y = fmaf(2.f, acc.y, p.y);
        acc.z = fmaf(2.f, acc.z, p.z); acc.w = fmaf(2.f, acc.w, p.w);
    } else if (MODE == 3) {
        float4 p = ((const float4*)x0)[idx];
        float4 q = ((const float4*)x1)[idx];
        acc.x += p.x - q.x; acc.y += p.y - q.y;
        acc.z += p.z - q.z; acc.w += p.w - q.w;
    }
    ((float4*)y)[idx] = acc;
}

// ---------------- SPMM C=64, bf16x8 (16B) per thread, 8 threads/row.
template<bool CHEB2, bool BNG, bool BNX0>
__global__ __launch_bounds__(256)
void spmm64_kernel(__bf16* __restrict__ y, const __bf16* __restrict__ x,
                   const __bf16* __restrict__ x0,
                   const float* __restrict__ val, const int* __restrict__ col,
                   const float* __restrict__ bn_a, const float* __restrict__ bn_b)
{
    int idx = blockIdx.x * 256 + threadIdx.x;   // over BV*8
    int q = idx % 8;
    int v = (idx / 8) % Nv;
    int b = idx / (8 * Nv);
    int e0 = v * NBRS;
    const bf16x8* x8 = (const bf16x8*)x;
    float4 aL, aH, bL, bH;
    if (BNG || (CHEB2 && BNX0)) {
        aL = ((const float4*)bn_a)[q * 2];     aH = ((const float4*)bn_a)[q * 2 + 1];
        bL = ((const float4*)bn_b)[q * 2];     bH = ((const float4*)bn_b)[q * 2 + 1];
    }
    float acc[8];
    #pragma unroll
    for (int t = 0; t < 8; ++t) acc[t] = 0.f;
    #pragma unroll
    for (int j = 0; j < NBRS; ++j) {
        int u = col[e0 + j];
        float a = val[e0 + j];
        bf16x8 hv = x8[(size_t)(b * Nv + u) * 8 + q];
        float xv[8];
        #pragma unroll
        for (int t = 0; t < 8; ++t) xv[t] = (float)hv[t];
        if (BNG) {
            xv[0] = fmaxf(fmaf(xv[0], aL.x, bL.x), 0.f);
            xv[1] = fmaxf(fmaf(xv[1], aL.y, bL.y), 0.f);
            xv[2] = fmaxf(fmaf(xv[2], aL.z, bL.z), 0.f);
            xv[3] = fmaxf(fmaf(xv[3], aL.w, bL.w), 0.f);
            xv[4] = fmaxf(fmaf(xv[4], aH.x, bH.x), 0.f);
            xv[5] = fmaxf(fmaf(xv[5], aH.y, bH.y), 0.f);
            xv[6] = fmaxf(fmaf(xv[6], aH.z, bH.z), 0.f);
            xv[7] = fmaxf(fmaf(xv[7], aH.w, bH.w), 0.f);
        }
        #pragma unroll
        for (int t = 0; t < 8; ++t) acc[t] = fmaf(a, xv[t], acc[t]);
    }
    if (CHEB2) {
        bf16x8 pv = ((const bf16x8*)x0)[idx];
        float p[8];
        #pragma unroll
        for (int t = 0; t < 8; ++t) p[t] = (float)pv[t];
        if (BNX0) {
            p[0] = fmaxf(fmaf(p[0], aL.x, bL.x), 0.f);
            p[1] = fmaxf(fmaf(p[1], aL.y, bL.y), 0.f);
            p[2] = fmaxf(fmaf(p[2], aL.z, bL.z), 0.f);
            p[3] = fmaxf(fmaf(p[3], aL.w, bL.w), 0.f);
            p[4] = fmaxf(fmaf(p[4], aH.x, bH.x), 0.f);
            p[5] = fmaxf(fmaf(p[5], aH.y, bH.y), 0.f);
            p[6] = fmaxf(fmaf(p[6], aH.z, bH.z), 0.f);
            p[7] = fmaxf(fmaf(p[7], aH.w, bH.w), 0.f);
        }
        #pragma unroll
        for (int t = 0; t < 8; ++t) acc[t] = 2.f * acc[t] - p[t];
    }
    bf16x8 o;
    #pragma unroll
    for (int t = 0; t < 8; ++t) o[t] = (__bf16)acc[t];
    ((bf16x8*)y)[idx] = o;
}

// ---------------- unified pack: all fp32 weights -> fragment-ordered bf16
// arena + conv3 padded bias. wp3 region maps directly from conv3_w.
__global__ __launch_bounds__(256)
void pack_all_kernel(const float* __restrict__ w1, const float* __restrict__ w2,
                     const float* __restrict__ c1, const float* __restrict__ c2,
                     const float* __restrict__ c3, const float* __restrict__ w3,
                     const float* __restrict__ b3,
                     __bf16* __restrict__ wb, float* __restrict__ bpack)
{
    int t = blockIdx.x * 256 + threadIdx.x;
    if (t >= 194560) {
        int i = t - 194560;
        if (i < 32) bpack[i] = (i < 8) ? b3[i] : 0.f;
        return;
    }
    const float* src; int KSRC, FOUT, local; bool isW3 = false;
    if (t < 2048)        { src = w1;  KSRC = 24;  FOUT = 64;  local = t; }
    else if (t < 51200)  { src = w2;  KSRC = 192; FOUT = 256; local = t - 2048; }
    else if (t < 100352) { int i = (t - 51200) / 16384;  src = c1 + (size_t)i * 16384;
                           KSRC = 256; FOUT = 64;  local = (t - 51200) % 16384; }
    else if (t < 137216) { int i = (t - 100352) / 12288; src = c2 + (size_t)i * 12288;
                           KSRC = 192; FOUT = 64;  local = (t - 100352) % 12288; }
    else if (t < 186368) { int i = (t - 137216) / 16384; src = c3 + (size_t)i * 16384;
                           KSRC = 64;  FOUT = 256; local = (t - 137216) % 16384; }
    else                 { src = w3;  KSRC = 256; FOUT = 32;  local = t - 186368; isW3 = true; }
    const int j    = local & 7;
    const int lane = (local >> 3) & 63;
    const int rest = local >> 9;
    const int NT = FOUT >> 4;
    const int nt = rest % NT;
    const int ks = rest / NT;
    const int k = ks * 32 + (lane >> 4) * 8 + j;
    const int o = nt * 16 + (lane & 15);
    float v;
    if (isW3) {
        v = (o < 24) ? src[(size_t)(o >> 3) * 2048 + k * 8 + (o & 7)] : 0.f;
    } else {
        v = (k < KSRC) ? src[(size_t)k * FOUT + o] : 0.f;
    }
    wb[t] = (__bf16)v;
}

// ---------------- MFMA GEMM. INBF: x bf16; OUTBF: write bf16.
// RESID (NSRC=1, INBF): stage = BN(x0) + x1 (both bf16; fused residual).
template<int FOUT, int KFIN, int KPAD, int FIN, int NSRC,
         bool STATS, bool BN0, bool HAS_BIAS, bool PACKOUT, bool INBF, bool OUTBF,
         bool RESID = false>
__global__ __launch_bounds__(256)
void gemm_mfma_kernel(const void* __restrict__ x0, const void* __restrict__ x1,
                      const void* __restrict__ x2,
                      const __bf16* __restrict__ wp, const float* __restrict__ bias,
                      const float* __restrict__ bn_a, const float* __restrict__ bn_b,
                      void* __restrict__ out, float2* __restrict__ partial)
{
    constexpr int NT    = FOUT / 16;
    constexpr int NSTEP = KPAD / 32;
    constexpr bool COLS = (NT % 4 == 0);
    constexpr int NT2   = COLS ? NT / 4 : NT;
    constexpr int LDKB  = KPAD + 8;
    constexpr int LDC   = FOUT + 4;
    constexpr size_t XS_B  = (size_t)64 * LDKB * 2;
    constexpr size_t RPK_B = COLS ? (size_t)16 * LDC * 4 : 0;
    constexpr size_t SMEM  = XS_B > RPK_B ? XS_B : RPK_B;
    __shared__ __align__(16) char smem[SMEM];
    __bf16* xs = (__bf16*)smem;

    const int tid = threadIdx.x;
    const int m0 = blockIdx.x * 64;

    constexpr int NF4 = 64 * (KPAD / 4);
    for (int f = tid; f < NF4; f += 256) {
        const int r  = f / (KPAD / 4);
        const int ki = (f % (KPAD / 4)) * 4;
        bf16x4 h;
        if (KFIN == KPAD || ki < KFIN) {
            int i; int kk;
            if constexpr (NSRC == 1) { i = ki; kk = 0; }
            else { kk = ki / FIN; i = ki % FIN; }
            if constexpr (RESID) {
                const __bf16* srcy = (const __bf16*)x0;
                const __bf16* srct = (const __bf16*)x1;
                bf16x4 hy = *(const bf16x4*)(srcy + (size_t)(m0 + r) * FIN + i);
                bf16x4 ht = *(const bf16x4*)(srct + (size_t)(m0 + r) * FIN + i);
                const float4 a4 = *(const float4*)(bn_a + i);
                const float4 b4 = *(const float4*)(bn_b + i);
                h[0] = (__bf16)(fmaf((float)hy[0], a4.x, b4.x) + (float)ht[0]);
                h[1] = (__bf16)(fmaf((float)hy[1], a4.y, b4.y) + (float)ht[1]);
                h[2] = (__bf16)(fmaf((float)hy[2], a4.z, b4.z) + (float)ht[2]);
                h[3] = (__bf16)(fmaf((float)hy[3], a4.w, b4.w) + (float)ht[3]);
            } else if constexpr (INBF) {
                const __bf16* src = (kk == 0) ? (const __bf16*)x0
                                  : (kk == 1 ? (const __bf16*)x1 : (const __bf16*)x2);
                bf16x4 hv = *(const bf16x4*)(src + (size_t)(m0 + r) * FIN + i);
                if (BN0 && (NSRC == 1 || kk == 0)) {
                    const float4 a4 = *(const float4*)(bn_a + i);
                    const float4 b4 = *(const float4*)(bn_b + i);
                    h[0] = (__bf16)fmaxf(fmaf((float)hv[0], a4.x, b4.x), 0.f);
                    h[1] = (__bf16)fmaxf(fmaf((float)hv[1], a4.y, b4.y), 0.f);
                    h[2] = (__bf16)fmaxf(fmaf((float)hv[2], a4.z, b4.z), 0.f);
                    h[3] = (__bf16)fmaxf(fmaf((float)hv[3], a4.w, b4.w), 0.f);
                } else {
                    h = hv;
                }
            } else {
                const float* src = (kk == 0) ? (const float*)x0
                                 : (kk == 1 ? (const float*)x1 : (const float*)x2);
                float4 v = *(const float4*)(src + (size_t)(m0 + r) * FIN + i);
                if (BN0 && (NSRC == 1 || kk == 0)) {
                    const float4 a4 = *(const float4*)(bn_a + i);
                    const float4 b4 = *(const float4*)(bn_b + i);
                    v.x = fmaxf(fmaf(v.x, a4.x, b4.x), 0.f);
                    v.y = fmaxf(fmaf(v.y, a4.y, b4.y), 0.f);
                    v.z = fmaxf(fmaf(v.z, a4.z, b4.z), 0.f);
                    v.w = fmaxf(fmaf(v.w, a4.w, b4.w), 0.f);
                }
                h[0] = (__bf16)v.x; h[1] = (__bf16)v.y; h[2] = (__bf16)v.z; h[3] = (__bf16)v.w;
            }
        } else {
            h[0] = (__bf16)0.f; h[1] = (__bf16)0.f; h[2] = (__bf16)0.f; h[3] = (__bf16)0.f;
        }
        *(bf16x4*)(xs + (size_t)r * LDKB + ki) = h;
    }
    __syncthreads();

    const int lane = tid & 63;
    const int wv   = tid >> 6;
    const int lo   = lane & 15;
    const int hi   = lane >> 4;

    if constexpr (COLS) {
        f32x4 acc[4][NT2];
        #pragma unroll
        for (int mr = 0; mr < 4; ++mr)
            #pragma unroll
            for (int n = 0; n < NT2; ++n) acc[mr][n] = (f32x4){0.f, 0.f, 0.f, 0.f};

        #pragma unroll
        for (int ks = 0; ks < NSTEP; ++ks) {
            bf16x8 bfr[NT2];
            #pragma unroll
            for (int n = 0; n < NT2; ++n)
                bfr[n] = *(const bf16x8*)(wp + ((size_t)(ks * NT + wv * NT2 + n) * 64 + lane) * 8);
            bf16x8 afr[4];
            #pragma unroll
            for (int mr = 0; mr < 4; ++mr)
                afr[mr] = *(const bf16x8*)(xs + (size_t)(mr * 16 + lo) * LDKB + ks * 32 + hi * 8);
            #pragma unroll
            for (int n = 0; n < NT2; ++n)
                #pragma unroll
                for (int mr = 0; mr < 4; ++mr)
                    acc[mr][n] = __builtin_amdgcn_mfma_f32_16x16x32_bf16(afr[mr], bfr[n], acc[mr][n], 0, 0, 0);
        }

        #pragma unroll
        for (int n = 0; n < NT2; ++n) {
            const int o = wv * (FOUT / 4) + n * 16 + lo;
            const float bo = HAS_BIAS ? bias[o] : 0.f;
            #pragma unroll
            for (int mr = 0; mr < 4; ++mr)
                #pragma unroll
                for (int j = 0; j < 4; ++j) acc[mr][n][j] += bo;
        }

        if constexpr (STATS) {
            #pragma unroll
            for (int n = 0; n < NT2; ++n) {
                float s = 0.f, q = 0.f;
                #pragma unroll
                for (int mr = 0; mr < 4; ++mr)
                    #pragma unroll
                    for (int j = 0; j < 4; ++j) {
                        const float v = acc[mr][n][j];
                        s += v; q = fmaf(v, v, q);
                    }
                s += __shfl_xor(s, 16); q += __shfl_xor(q, 16);
                s += __shfl_xor(s, 32); q += __shfl_xor(q, 32);
                if (lane < 16) {
                    const int o = wv * (FOUT / 4) + n * 16 + lo;
                    partial[(size_t)o * gridDim.x + blockIdx.x] = make_float2(s, q);
                }
            }
        }

        float* cs = (float*)smem;
        #pragma unroll
        for (int mr = 0; mr < 4; ++mr) {
            __syncthreads();
            #pragma unroll
            for (int n = 0; n < NT2; ++n) {
                const int o = wv * (FOUT / 4) + n * 16 + lo;
                #pragma unroll
                for (int j = 0; j < 4; ++j)
                    cs[(size_t)(hi * 4 + j) * LDC + o] = acc[mr][n][j];
            }
            __syncthreads();
            for (int t = tid; t < 16 * (FOUT / 4); t += 256) {
                const int rr = t / (FOUT / 4);
                const int c4 = (t % (FOUT / 4)) * 4;
                const float4 v = *(const float4*)(cs + (size_t)rr * LDC + c4);
                if constexpr (OUTBF) {
                    bf16x4 hv;
                    hv[0] = (__bf16)v.x; hv[1] = (__bf16)v.y;
                    hv[2] = (__bf16)v.z; hv[3] = (__bf16)v.w;
                    *(bf16x4*)((__bf16*)out + (size_t)(m0 + mr * 16 + rr) * FOUT + c4) = hv;
                } else {
                    *(float4*)((float*)out + (size_t)(m0 + mr * 16 + rr) * FOUT + c4) = v;
                }
            }
        }
    } else {
        f32x4 acc[NT];
        #pragma unroll
        for (int nt = 0; nt < NT; ++nt) acc[nt] = (f32x4){0.f, 0.f, 0.f, 0.f};
        const int arow = wv * 16 + lo;
        #pragma unroll
        for (int ks = 0; ks < NSTEP; ++ks) {
            const bf16x8 a = *(const bf16x8*)(xs + (size_t)arow * LDKB + ks * 32 + hi * 8);
            #pragma unroll
            for (int nt = 0; nt < NT; ++nt) {
                const bf16x8 b = *(const bf16x8*)(wp + ((size_t)(ks * NT + nt) * 64 + lane) * 8);
                acc[nt] = __builtin_amdgcn_mfma_f32_16x16x32_bf16(a, b, acc[nt], 0, 0, 0);
            }
        }
        #pragma unroll
        for (int nt = 0; nt < NT; ++nt) {
            const int o = nt * 16 + lo;
            const float bo = HAS_BIAS ? bias[o] : 0.f;
            #pragma unroll
            for (int j = 0; j < 4; ++j) {
                const float v = acc[nt][j] + bo;
                const int m = m0 + wv * 16 + hi * 4 + j;
                if constexpr (PACKOUT) {
                    const int zj = o >> 3;
                    if (zj < 3) ((float*)out)[((size_t)zj * BV + m) * 8 + (o & 7)] = v;
                } else {
                    ((float*)out)[(size_t)m * FOUT + o] = v;
                }
            }
        }
    }
}

// ---------------- BN finalize: one block per channel, coalesced over [C][nblk]
__global__ __launch_bounds__(256)
void bn_finalize_kernel(const float2* __restrict__ partial,
                        const float* __restrict__ g, const float* __restrict__ b,
                        float* __restrict__ a_out, float* __restrict__ b_out,
                        float invN, int nblk)
{
    __shared__ float2 red[4];
    const int c = blockIdx.x;
    const float2* p = partial + (size_t)c * nblk;
    float s = 0.f, ss = 0.f;
    for (int k = threadIdx.x; k < nblk; k += 256) {
        const float2 v = p[k];
        s += v.x; ss += v.y;
    }
    #pragma unroll
    for (int off = 32; off > 0; off >>= 1) {
        s  += __shfl_down(s, off);
        ss += __shfl_down(ss, off);
    }
    if ((threadIdx.x & 63) == 0) red[threadIdx.x >> 6] = make_float2(s, ss);
    __syncthreads();
    if (threadIdx.x == 0) {
        float ts = 0.f, tq = 0.f;
        #pragma unroll
        for (int i = 0; i < 4; ++i) { ts += red[i].x; tq += red[i].y; }
        const float m = ts * invN;
        const float var = tq * invN - m * m;
        const float a = g[c] * rsqrtf(var + BN_EPS);
        a_out[c] = a;
        b_out[c] = b[c] - m * a;
    }
}

// ---------------- BN apply: all-bf16 trunk update. out = BN3(x) + baseproc.
template<int C, bool BASEBN>
__global__ __launch_bounds__(256)
void bn_apply_kernel(__bf16* __restrict__ out, const __bf16* __restrict__ x,
                     const __bf16* __restrict__ base,
                     const float* __restrict__ bn_a, const float* __restrict__ bn_b,
                     const float* __restrict__ bn_a2, const float* __restrict__ bn_b2)
{
    int i = blockIdx.x * 256 + threadIdx.x;   // 4-elem index
    bf16x4 hv = ((const bf16x4*)x)[i];
    int c0 = (i * 4) % C;
    float4 a4 = *reinterpret_cast<const float4*>(bn_a + c0);
    float4 b4 = *reinterpret_cast<const float4*>(bn_b + c0);
    float r0 = fmaf((float)hv[0], a4.x, b4.x);
    float r1 = fmaf((float)hv[1], a4.y, b4.y);
    float r2 = fmaf((float)hv[2], a4.z, b4.z);
    float r3 = fmaf((float)hv[3], a4.w, b4.w);
    bf16x4 bb = ((const bf16x4*)base)[i];
    float v0 = (float)bb[0], v1 = (float)bb[1], v2 = (float)bb[2], v3 = (float)bb[3];
    if (BASEBN) {
        float4 p4 = *reinterpret_cast<const float4*>(bn_a2 + c0);
        float4 q4 = *reinterpret_cast<const float4*>(bn_b2 + c0);
        v0 = fmaxf(fmaf(v0, p4.x, q4.x), 0.f);
        v1 = fmaxf(fmaf(v1, p4.y, q4.y), 0.f);
        v2 = fmaxf(fmaf(v2, p4.z, q4.z), 0.f);
        v3 = fmaxf(fmaf(v3, p4.w, q4.w), 0.f);
    }
    bf16x4 o;
    o[0] = (__bf16)(r0 + v0);
    o[1] = (__bf16)(r1 + v1);
    o[2] = (__bf16)(r2 + v2);
    o[3] = (__bf16)(r3 + v3);
    ((bf16x4*)out)[i] = o;
}

extern "C" void kernel_launch(void* const* d_in, const int* in_sizes, int n_in,
                              void* d_out, int out_size, void* d_ws, size_t ws_size,
                              hipStream_t stream)
{
    const float* x       = (const float*)d_in[0];
    const int*   col     = (const int*)  d_in[2];
    const float* eval_   = (const float*)d_in[3];
    const float* conv1_w = (const float*)d_in[4];
    const float* conv1_b = (const float*)d_in[5];
    const float* bn1_g   = (const float*)d_in[6];
    const float* bn1_b   = (const float*)d_in[7];
    const float* conv2_w = (const float*)d_in[8];
    const float* conv2_b = (const float*)d_in[9];
    const float* bn2_g   = (const float*)d_in[10];
    const float* bn2_b   = (const float*)d_in[11];
    const float* bt_c1w  = (const float*)d_in[12];
    const float* bt_c1b  = (const float*)d_in[13];
    const float* bt_c2w  = (const float*)d_in[14];
    const float* bt_c2b  = (const float*)d_in[15];
    const float* bt_c3w  = (const float*)d_in[16];
    const float* bt_c3b  = (const float*)d_in[17];
    const float* btbn1g  = (const float*)d_in[18];
    const float* btbn1b  = (const float*)d_in[19];
    const float* btbn2g  = (const float*)d_in[20];
    const float* btbn2b  = (const float*)d_in[21];
    const float* btbn3g  = (const float*)d_in[22];
    const float* btbn3b  = (const float*)d_in[23];
    const float* conv3_w = (const float*)d_in[24];
    const float* conv3_b = (const float*)d_in[25];
    float* out = (float*)d_out;

    __bf16* h2b  = (__bf16*)d_ws;                  // BV*256 bf16 (trunk)
    __bf16* y3b  = h2b + (size_t)BV * 256;         // BV*256 bf16 (cheb3 out)
    __bf16* t64a = y3b + (size_t)BV * 256;         // 4 x BV*64 bf16
    __bf16* t64b = t64a + (size_t)BV * 64;
    __bf16* t64c = t64b + (size_t)BV * 64;
    __bf16* t64d = t64c + (size_t)BV * 64;
    float*  scr  = (float*)(t64d + (size_t)BV * 64);   // BV*32 fp32
    float*  aarr = scr + (size_t)BV * 32;          // 11*256
    float*  barr = aarr + 11 * 256;                // 11*256
    float*  bpack = barr + 11 * 256;               // 32
    __bf16* wb   = (__bf16*)(bpack + 32);          // bf16 weight arena
    __bf16* wp1  = wb;                             // 2048
    __bf16* wp2  = wp1 + 2048;                     // 49152
    __bf16* wpc1 = wp2 + 49152;                    // 49152
    __bf16* wpc2 = wpc1 + 49152;                   // 36864
    __bf16* wpc3 = wpc2 + 36864;                   // 49152
    __bf16* wp3  = wpc3 + 49152;                   // 8192
    float2* part = (float2*)(wp3 + 8192);          // 256 * 768

    float* t8a = scr;                              // BV*8 (stage A)
    float* t8b = scr + (size_t)BV * 8;

    const float invN = 1.f / (float)BV;
    const int NGB  = BV / 64;                      // 768
    const int NSP64 = BV * 8 / 256;                // 1536
    const int NSP8  = BV * 2 / 256;                // 384

    // ---------- packing: 1 launch ----------
    pack_all_kernel<<<761, 256, 0, stream>>>(conv1_w, conv2_w, bt_c1w, bt_c2w, bt_c3w,
                                             conv3_w, conv3_b, wb, bpack);

    // ---------- Stage A: conv1 (8 -> 64), K=3 (fp32 in, bf16 out) ----------
    spmm8_kernel<0><<<NSP8, 256, 0, stream>>>(t8a, x, nullptr, nullptr, eval_, col);
    spmm8_kernel<1><<<NSP8, 256, 0, stream>>>(t8b, t8a, x, nullptr, eval_, col);
    gemm_mfma_kernel<64, 24, 32, 8, 3, true, false, true, false, false, true>
        <<<NGB, 256, 0, stream>>>(x, t8a, t8b, wp1, conv1_b, nullptr, nullptr, t64c, part);
    bn_finalize_kernel<<<64, 256, 0, stream>>>(part, bn1_g, bn1_b, aarr, barr, invN, NGB);

    // ---------- Stage B: conv2 (64 -> 256), K=3; h2b RAW bf16 ----------
    spmm64_kernel<false, true, false><<<NSP64, 256, 0, stream>>>(t64a, t64c, nullptr, eval_, col, aarr, barr);
    spmm64_kernel<true, false, true ><<<NSP64, 256, 0, stream>>>(t64b, t64a, t64c, eval_, col, aarr, barr);
    gemm_mfma_kernel<256, 192, 192, 64, 3, true, true, true, false, true, true>
        <<<NGB, 256, 0, stream>>>(t64c, t64a, t64b, wp2, conv2_b, aarr, barr, h2b, part);
    bn_finalize_kernel<<<256, 256, 0, stream>>>(part, bn2_g, bn2_b, aarr + 256, barr + 256, invN, NGB);

    // ---------- Stage C: 3 bottlenecks ----------
    for (int i = 0; i < 3; ++i) {
        float* aA = aarr + (2 + i * 3) * 256; float* bA = barr + (2 + i * 3) * 256;
        float* aB = aarr + (3 + i * 3) * 256; float* bB = barr + (3 + i * 3) * 256;
        float* aC = aarr + (4 + i * 3) * 256; float* bC = barr + (4 + i * 3) * 256;

        // cheb1: 256->64, h2b bf16 in (BN2 fused for i=0), t64c bf16 out
        if (i == 0)
            gemm_mfma_kernel<64, 256, 256, 256, 1, true, true, true, false, true, true>
                <<<NGB, 256, 0, stream>>>(h2b, nullptr, nullptr, wpc1,
                                          bt_c1b, aarr + 256, barr + 256, t64c, part);
        else
            gemm_mfma_kernel<64, 256, 256, 256, 1, true, false, true, false, true, true>
                <<<NGB, 256, 0, stream>>>(h2b, nullptr, nullptr, wpc1 + (size_t)i * 16384,
                                          bt_c1b + i * 64, nullptr, nullptr, t64c, part);
        bn_finalize_kernel<<<64, 256, 0, stream>>>(part, btbn1g + i * 64, btbn1b + i * 64, aA, bA, invN, NGB);

        // cheb2: K=3, 64->64, all bf16; BN1 fused into gathers and x0-staging
        spmm64_kernel<false, true, false><<<NSP64, 256, 0, stream>>>(t64a, t64c, nullptr, eval_, col, aA, bA);
        spmm64_kernel<true, false, true ><<<NSP64, 256, 0, stream>>>(t64b, t64a, t64c, eval_, col, aA, bA);
        gemm_mfma_kernel<64, 192, 192, 64, 3, true, true, true, false, true, true>
            <<<NGB, 256, 0, stream>>>(t64c, t64a, t64b, wpc2 + (size_t)i * 12288,
                                      bt_c2b + i * 64, aA, bA, t64d, part);
        bn_finalize_kernel<<<64, 256, 0, stream>>>(part, btbn2g + i * 64, btbn2b + i * 64, aB, bB, invN, NGB);

        // cheb3: 64->256, t64d bf16 in (BN2 fused), y3b bf16 out
        gemm_mfma_kernel<256, 64, 64, 64, 1, true, true, true, false, true, true>
            <<<NGB, 256, 0, stream>>>(t64d, nullptr, nullptr, wpc3 + (size_t)i * 16384,
                                      bt_c3b + i * 256, aB, bB, y3b, part);
        bn_finalize_kernel<<<256, 256, 0, stream>>>(part, btbn3g + i * 256, btbn3b + i * 256, aC, bC, invN, NGB);

        // residual trunk update (skip i=2: fused into conv3 staging)
        if (i == 0)
            bn_apply_kernel<256, true><<<BV / 4, 256, 0, stream>>>(
                h2b, y3b, h2b, aC, bC, aarr + 256, barr + 256);
        else if (i == 1)
            bn_apply_kernel<256, false><<<BV / 4, 256, 0, stream>>>(
                h2b, y3b, h2b, aC, bC, nullptr, nullptr);
    }

    // ---------- Stage D: conv3 with fused final residual (RESID staging) ----------
    float* z0 = scr;
    float* z1 = z0 + (size_t)BV * 8;
    float* z2 = z1 + (size_t)BV * 8;
    float* ee = z2 + (size_t)BV * 8;
    float* aC2 = aarr + 10 * 256;   // i=2 BN3 params
    float* bC2 = barr + 10 * 256;

    gemm_mfma_kernel<32, 256, 256, 256, 1, false, true, true, true, true, false, true>
        <<<NGB, 256, 0, stream>>>(y3b, h2b, nullptr, wp3, bpack, aC2, bC2, z0, nullptr);

    spmm8_kernel<2><<<NSP8, 256, 0, stream>>>(ee, z2, z1, nullptr, eval_, col);
    spmm8_kernel<3><<<NSP8, 256, 0, stream>>>(out, ee, z0, z2, eval_, col);

    (void)in_sizes; (void)n_in; (void)out_size; (void)ws_size;
}